// Round 3
// baseline (1949.553 us; speedup 1.0000x reference)
//
#include <hip/hip_runtime.h>
#include <hip/hip_bf16.h>
#include <math.h>

// Problem constants (fixed by reference): N=100000 nodes, E=1.6M edges, H=256, T=64.

static inline size_t align512(size_t x){ return (x + 511) & ~size_t(511); }

typedef _Float16 h2_t __attribute__((ext_vector_type(2)));

#if defined(__has_builtin)
#if __has_builtin(__builtin_amdgcn_fdot2)
#define HAS_FDOT2 1
#endif
#endif

// ---------- CSR build ----------

__global__ void count_kernel(const int* __restrict__ ei, int* __restrict__ cnt, int E){
  int e = blockIdx.x*256 + threadIdx.x;
  if (e < E) atomicAdd(&cnt[ei[E + e]], 1);
}

__global__ void dis_kernel(const int* __restrict__ cnt, float* __restrict__ dis, int N){
  int i = blockIdx.x*256 + threadIdx.x;
  if (i < N) dis[i] = rsqrtf((float)cnt[i] + 1.0f);
}

__global__ void scan_block_kernel(const int* __restrict__ cnt, int* __restrict__ rp,
                                  int* __restrict__ bsum, int N){
  __shared__ int s[2][1024];
  int t = threadIdx.x; int i = blockIdx.x*1024 + t;
  int v = (i < N) ? cnt[i] : 0;
  int cur = 0; s[0][t] = v; __syncthreads();
  for (int off = 1; off < 1024; off <<= 1){
    int nxt = cur ^ 1;
    int val = s[cur][t];
    if (t >= off) val += s[cur][t - off];
    s[nxt][t] = val; cur = nxt; __syncthreads();
  }
  if (i < N) rp[i+1] = s[cur][t];
  if (t == 1023) bsum[blockIdx.x] = s[cur][1023];
}

__global__ void scan_sums_kernel(int* __restrict__ bsum, int nb){
  __shared__ int s[128];
  int t = threadIdx.x;
  if (t < nb) s[t] = bsum[t];
  __syncthreads();
  if (t == 0){ int acc = 0; for (int b = 0; b < nb; b++){ int v = s[b]; s[b] = acc; acc += v; } }
  __syncthreads();
  if (t < nb) bsum[t] = s[t];
}

__global__ void add_off_kernel(int* __restrict__ rp, const int* __restrict__ bsum,
                               int* __restrict__ cnt, int N){
  int i = blockIdx.x*256 + threadIdx.x;
  if (i < N){ rp[i+1] += bsum[i >> 10]; cnt[i] = 0; }
  if (i == 0) rp[0] = 0;
}

__global__ void fill_kernel(const int* __restrict__ ei, const int* __restrict__ rp,
                            int* __restrict__ cnt, int* __restrict__ csrc, int E){
  int e = blockIdx.x*256 + threadIdx.x;
  if (e < E){
    int s = ei[e]; int d = ei[E + e];
    int pos = rp[d] + atomicAdd(&cnt[d], 1);
    csrc[pos] = s;
  }
}

// ---------- GEMM: out[N,256] = A[N,256] @ W[256,256] (no bias) ----------
// Register-blocked LDS tiling: BM=BN=128, BK=16, 256 threads, 8x8 out/thread.

__global__ __launch_bounds__(256) void gemm_kernel(const float* __restrict__ A,
                                                   const float* __restrict__ W,
                                                   float* __restrict__ out, int N){
  __shared__ float As[16][132];   // As[k][m]  (transposed A tile)
  __shared__ float Bs[16][132];   // Bs[k][c]
  int tid = threadIdx.x;
  int tx = tid & 15, ty = tid >> 4;
  int r0 = blockIdx.x * 128;
  int c0 = blockIdx.y * 128;

  int am = tid >> 2;
  int ak = (tid & 3) << 2;
  int bk = tid >> 5;
  int bc = (tid & 31) << 2;

  int arow0 = min(r0 + am, N - 1);
  int arow1 = min(r0 + 64 + am, N - 1);

  float4 acc[2][2][4];
  #pragma unroll
  for (int a = 0; a < 2; a++)
    #pragma unroll
    for (int b = 0; b < 2; b++)
      #pragma unroll
      for (int i = 0; i < 4; i++)
        acc[a][b][i] = make_float4(0.f, 0.f, 0.f, 0.f);

  for (int kb = 0; kb < 256; kb += 16){
    float4 av0 = *(const float4*)&A[(size_t)arow0*256 + kb + ak];
    float4 av1 = *(const float4*)&A[(size_t)arow1*256 + kb + ak];
    As[ak+0][am]      = av0.x; As[ak+1][am]      = av0.y;
    As[ak+2][am]      = av0.z; As[ak+3][am]      = av0.w;
    As[ak+0][64+am]   = av1.x; As[ak+1][64+am]   = av1.y;
    As[ak+2][64+am]   = av1.z; As[ak+3][64+am]   = av1.w;
    float4 bv0 = *(const float4*)&W[(size_t)(kb + bk)*256 + c0 + bc];
    float4 bv1 = *(const float4*)&W[(size_t)(kb + bk + 8)*256 + c0 + bc];
    *(float4*)&Bs[bk][bc]     = bv0;
    *(float4*)&Bs[bk+8][bc]   = bv1;
    __syncthreads();

    #pragma unroll
    for (int k = 0; k < 16; k++){
      float4 a0 = *(const float4*)&As[k][ty*4];
      float4 a1 = *(const float4*)&As[k][64 + ty*4];
      float4 b0 = *(const float4*)&Bs[k][tx*4];
      float4 b1 = *(const float4*)&Bs[k][64 + tx*4];
      const float* ap0 = (const float*)&a0;
      const float* ap1 = (const float*)&a1;
      #pragma unroll
      for (int i = 0; i < 4; i++){
        float r0v = ap0[i], r1v = ap1[i];
        acc[0][0][i].x = fmaf(r0v, b0.x, acc[0][0][i].x);
        acc[0][0][i].y = fmaf(r0v, b0.y, acc[0][0][i].y);
        acc[0][0][i].z = fmaf(r0v, b0.z, acc[0][0][i].z);
        acc[0][0][i].w = fmaf(r0v, b0.w, acc[0][0][i].w);
        acc[0][1][i].x = fmaf(r0v, b1.x, acc[0][1][i].x);
        acc[0][1][i].y = fmaf(r0v, b1.y, acc[0][1][i].y);
        acc[0][1][i].z = fmaf(r0v, b1.z, acc[0][1][i].z);
        acc[0][1][i].w = fmaf(r0v, b1.w, acc[0][1][i].w);
        acc[1][0][i].x = fmaf(r1v, b0.x, acc[1][0][i].x);
        acc[1][0][i].y = fmaf(r1v, b0.y, acc[1][0][i].y);
        acc[1][0][i].z = fmaf(r1v, b0.z, acc[1][0][i].z);
        acc[1][0][i].w = fmaf(r1v, b0.w, acc[1][0][i].w);
        acc[1][1][i].x = fmaf(r1v, b1.x, acc[1][1][i].x);
        acc[1][1][i].y = fmaf(r1v, b1.y, acc[1][1][i].y);
        acc[1][1][i].z = fmaf(r1v, b1.z, acc[1][1][i].z);
        acc[1][1][i].w = fmaf(r1v, b1.w, acc[1][1][i].w);
      }
    }
    __syncthreads();
  }

  #pragma unroll
  for (int rb = 0; rb < 2; rb++){
    #pragma unroll
    for (int i = 0; i < 4; i++){
      int r = r0 + rb*64 + ty*4 + i;
      if (r < N){
        *(float4*)&out[(size_t)r*256 + c0 + tx*4]      = acc[rb][0][i];
        *(float4*)&out[(size_t)r*256 + c0 + 64 + tx*4] = acc[rb][1][i];
      }
    }
  }
}

// ---------- GCN aggregation ----------

__global__ __launch_bounds__(256) void agg_kernel(const float* __restrict__ xw,
                                                  const float* __restrict__ dis,
                                                  const int* __restrict__ rp,
                                                  const int* __restrict__ csrc,
                                                  const float* __restrict__ bias,
                                                  float* __restrict__ out, int N){
  int node = blockIdx.x*4 + (threadIdx.x >> 6);
  int lane = threadIdx.x & 63;
  if (node >= N) return;
  const float4* xw4 = (const float4*)xw;
  float di = dis[node];
  float4 a = xw4[(size_t)node*64 + lane];
  float sc = di * di;
  float4 acc;
  acc.x = a.x*sc; acc.y = a.y*sc; acc.z = a.z*sc; acc.w = a.w*sc;
  int e0 = rp[node], e1 = rp[node+1];
  for (int e = e0; e < e1; e++){
    int s = csrc[e];
    float cc = dis[s] * di;
    float4 v = xw4[(size_t)s*64 + lane];
    acc.x = fmaf(v.x, cc, acc.x);
    acc.y = fmaf(v.y, cc, acc.y);
    acc.z = fmaf(v.z, cc, acc.z);
    acc.w = fmaf(v.w, cc, acc.w);
  }
  const float4* b4 = (const float4*)bias;
  float4 b = b4[lane];
  acc.x = fmaxf(acc.x + b.x, 0.f);
  acc.y = fmaxf(acc.y + b.y, 0.f);
  acc.z = fmaxf(acc.z + b.z, 0.f);
  acc.w = fmaxf(acc.w + b.w, 0.f);
  ((float4*)out)[(size_t)node*64 + lane] = acc;
}

// ---------- mean pool ----------

__global__ void pool_kernel(const float* __restrict__ h, const int* __restrict__ ptr,
                            float* __restrict__ hp){
  int t = blockIdx.x; int part = blockIdx.y; int c = threadIdx.x;
  int s0 = ptr[t], s1 = ptr[t+1];
  int len = s1 - s0;
  int chunk = (len + 7) / 8;
  int r0 = s0 + part*chunk;
  int r1 = min(r0 + chunk, s1);
  float acc = 0.f;
  for (int r = r0; r < r1; r++) acc += h[(size_t)r*256 + c];
  if (r1 > r0) atomicAdd(&hp[t*256 + c], acc);
}

__global__ void hp_div_kernel(float* __restrict__ hp, const int* __restrict__ ptr){
  int t = blockIdx.x; int c = threadIdx.x;
  float cf = (float)max(ptr[t+1] - ptr[t], 1);
  hp[t*256 + c] /= cf;
}

// ---------- GX[t,g] = dot(hp[t], w_ih[g]) + b_ih[g] ----------

__global__ __launch_bounds__(768) void gx_kernel(const float* __restrict__ hp,
                                                 const float* __restrict__ wih,
                                                 const float* __restrict__ bih,
                                                 float* __restrict__ gx){
  __shared__ float xs[256];
  int t = blockIdx.x; int g = threadIdx.x;
  if (g < 256) xs[g] = hp[t*256 + g];
  __syncthreads();
  float acc = bih[g];
  const float* wr = wih + (size_t)g*256;
  #pragma unroll 4
  for (int k = 0; k < 256; k++) acc = fmaf(xs[k], wr[k], acc);
  gx[t*768 + g] = acc;
}

// ---------- sequential GRU: single block, 512 threads, w_hh register-resident f16 ----------
// thread (i = tid>>1, half = tid&1) owns rows i, i+256, i+512 of w_hh over k-slice
// [half*128, half*128+128). Dots via v_dot2_f32_f16 from register weights + LDS h(f16).
// Pair-reduce with shfl_xor(1); both lanes compute gates redundantly (no divergence).

__global__ __launch_bounds__(512, 2) void gru_kernel(const float* __restrict__ gx,
                                                     const float* __restrict__ whh,
                                                     const float* __restrict__ bhh,
                                                     const float* __restrict__ Wc,
                                                     const float* __restrict__ bc,
                                                     float* __restrict__ out){
  __shared__ _Float16 hh[256];
  __shared__ float hfin[256];
  int tid = threadIdx.x;
  int i = tid >> 1;        // gate index 0..255
  int half = tid & 1;      // k-half

  // preload weight slices into registers as f16 pairs
  h2_t wr[64], wz[64], wn[64];
  {
    const float2* w2 = (const float2*)whh;
    size_t base = (size_t)half * 64;
    #pragma unroll 8
    for (int k = 0; k < 64; k++){
      float2 a = w2[(size_t)i*128       + base + k];
      float2 b = w2[(size_t)(i+256)*128 + base + k];
      float2 c = w2[(size_t)(i+512)*128 + base + k];
      wr[k] = h2_t{(_Float16)a.x, (_Float16)a.y};
      wz[k] = h2_t{(_Float16)b.x, (_Float16)b.y};
      wn[k] = h2_t{(_Float16)c.x, (_Float16)c.y};
    }
  }
  float bR = bhh[i], bZ = bhh[i+256], bN = bhh[i+512];
  float h = 0.f;

  for (int t = 0; t < 64; t++){
    if (half == 0) hh[i] = (_Float16)h;
    __syncthreads();
    float gxr = gx[t*768 + i];
    float gxz = gx[t*768 + 256 + i];
    float gxn = gx[t*768 + 512 + i];
    const h2_t* hp2 = ((const h2_t*)hh) + half*64;
    float accR = 0.f, accZ = 0.f, accN = 0.f;
    #pragma unroll
    for (int k = 0; k < 64; k++){
      h2_t hv = hp2[k];
#ifdef HAS_FDOT2
      accR = __builtin_amdgcn_fdot2(hv, wr[k], accR, false);
      accZ = __builtin_amdgcn_fdot2(hv, wz[k], accZ, false);
      accN = __builtin_amdgcn_fdot2(hv, wn[k], accN, false);
#else
      accR = fmaf((float)hv.x, (float)wr[k].x, accR);
      accR = fmaf((float)hv.y, (float)wr[k].y, accR);
      accZ = fmaf((float)hv.x, (float)wz[k].x, accZ);
      accZ = fmaf((float)hv.y, (float)wz[k].y, accZ);
      accN = fmaf((float)hv.x, (float)wn[k].x, accN);
      accN = fmaf((float)hv.y, (float)wn[k].y, accN);
#endif
    }
    accR += __shfl_xor(accR, 1);
    accZ += __shfl_xor(accZ, 1);
    accN += __shfl_xor(accN, 1);
    // gates (both lanes compute identically; b_hh n-bias goes inside r*(.))
    float r = 1.f/(1.f + expf(-(gxr + accR + bR)));
    float z = 1.f/(1.f + expf(-(gxz + accZ + bZ)));
    float n = tanhf(gxn + r*(accN + bN));
    float hnew = (1.f - z)*n + z*h;
    __syncthreads();   // all reads of hh done before next-iter write
    h = hnew;
  }

  if (half == 0) hfin[i] = h;
  __syncthreads();
  if (tid < 16){
    float acc = bc[tid];
    const float* wrow = Wc + (size_t)tid*256;
    for (int k = 0; k < 256; k++) acc = fmaf(hfin[k], wrow[k], acc);
    out[tid] = acc;
  }
}

extern "C" void kernel_launch(void* const* d_in, const int* in_sizes, int n_in,
                              void* d_out, int out_size, void* d_ws, size_t ws_size,
                              hipStream_t stream){
  const float* x   = (const float*)d_in[0];
  const int*   ei  = (const int*)d_in[1];
  const int*   ptr = (const int*)d_in[2];
  const float* W1  = (const float*)d_in[3];
  const float* b1  = (const float*)d_in[4];
  const float* W2  = (const float*)d_in[5];
  const float* b2  = (const float*)d_in[6];
  const float* wih = (const float*)d_in[7];
  const float* whh = (const float*)d_in[8];
  const float* bih = (const float*)d_in[9];
  const float* bhh = (const float*)d_in[10];
  const float* Wc  = (const float*)d_in[11];
  const float* bc  = (const float*)d_in[12];
  float* outp = (float*)d_out;

  const int N = in_sizes[0] / 256;   // 100000
  const int E = in_sizes[1] / 2;     // 1600000

  char* w = (char*)d_ws;
  size_t off = 0;
  auto alloc = [&](size_t bytes){ void* p = w + off; off = align512(off + bytes); return p; };
  float* bufA = (float*)alloc((size_t)N*256*4);   // xw
  float* bufB = (float*)alloc((size_t)N*256*4);   // h (post-agg)
  float* dis  = (float*)alloc((size_t)N*4);
  int*   cnt  = (int*)  alloc((size_t)N*4);
  int*   rp   = (int*)  alloc((size_t)(N+1)*4);
  int*   bsum = (int*)  alloc(128*4);
  int*   csrc = (int*)  alloc((size_t)E*4);
  float* hp   = (float*)alloc((size_t)64*256*4);
  float* gxb  = (float*)alloc((size_t)64*768*4);
  (void)ws_size; (void)n_in; (void)out_size;

  hipMemsetAsync(cnt, 0, (size_t)N*4, stream);
  hipMemsetAsync(hp,  0, (size_t)64*256*4, stream);

  // CSR build + degree
  count_kernel<<<(E+255)/256, 256, 0, stream>>>(ei, cnt, E);
  dis_kernel<<<(N+255)/256, 256, 0, stream>>>(cnt, dis, N);
  int nb = (N + 1023) / 1024;
  scan_block_kernel<<<nb, 1024, 0, stream>>>(cnt, rp, bsum, N);
  scan_sums_kernel<<<1, 128, 0, stream>>>(bsum, nb);
  add_off_kernel<<<(N+255)/256, 256, 0, stream>>>(rp, bsum, cnt, N);
  fill_kernel<<<(E+255)/256, 256, 0, stream>>>(ei, rp, cnt, csrc, E);

  // GCN layer 1
  gemm_kernel<<<dim3((N+127)/128, 2), 256, 0, stream>>>(x, W1, bufA, N);
  agg_kernel<<<(N+3)/4, 256, 0, stream>>>(bufA, dis, rp, csrc, b1, bufB, N);
  // GCN layer 2
  gemm_kernel<<<dim3((N+127)/128, 2), 256, 0, stream>>>(bufB, W2, bufA, N);
  agg_kernel<<<(N+3)/4, 256, 0, stream>>>(bufA, dis, rp, csrc, b2, bufB, N);

  // pool + GRU + classifier
  pool_kernel<<<dim3(64, 8), 256, 0, stream>>>(bufB, ptr, hp);
  hp_div_kernel<<<64, 256, 0, stream>>>(hp, ptr);
  gx_kernel<<<64, 768, 0, stream>>>(hp, wih, bih, gxb);
  gru_kernel<<<1, 512, 0, stream>>>(gxb, whh, bhh, Wc, bc, outp);
}

// Round 4
// 1321.964 us; speedup vs baseline: 1.4747x; 1.4747x over previous
//
#include <hip/hip_runtime.h>
#include <hip/hip_bf16.h>
#include <math.h>

// Problem constants (fixed by reference): N=100000 nodes, E=1.6M edges, H=256, T=64.

static inline size_t align512(size_t x){ return (x + 511) & ~size_t(511); }

typedef _Float16 h2_t __attribute__((ext_vector_type(2)));

#if defined(__has_builtin)
#if __has_builtin(__builtin_amdgcn_fdot2)
#define HAS_FDOT2 1
#endif
#endif

// ---------- CSR build ----------

__global__ void count_kernel(const int* __restrict__ ei, int* __restrict__ cnt, int E){
  int e = blockIdx.x*256 + threadIdx.x;
  if (e < E) atomicAdd(&cnt[ei[E + e]], 1);
}

__global__ void dis_kernel(const int* __restrict__ cnt, float* __restrict__ dis, int N){
  int i = blockIdx.x*256 + threadIdx.x;
  if (i < N) dis[i] = rsqrtf((float)cnt[i] + 1.0f);
}

__global__ void scan_block_kernel(const int* __restrict__ cnt, int* __restrict__ rp,
                                  int* __restrict__ bsum, int N){
  __shared__ int s[2][1024];
  int t = threadIdx.x; int i = blockIdx.x*1024 + t;
  int v = (i < N) ? cnt[i] : 0;
  int cur = 0; s[0][t] = v; __syncthreads();
  for (int off = 1; off < 1024; off <<= 1){
    int nxt = cur ^ 1;
    int val = s[cur][t];
    if (t >= off) val += s[cur][t - off];
    s[nxt][t] = val; cur = nxt; __syncthreads();
  }
  if (i < N) rp[i+1] = s[cur][t];
  if (t == 1023) bsum[blockIdx.x] = s[cur][1023];
}

__global__ void scan_sums_kernel(int* __restrict__ bsum, int nb){
  __shared__ int s[128];
  int t = threadIdx.x;
  if (t < nb) s[t] = bsum[t];
  __syncthreads();
  if (t == 0){ int acc = 0; for (int b = 0; b < nb; b++){ int v = s[b]; s[b] = acc; acc += v; } }
  __syncthreads();
  if (t < nb) bsum[t] = s[t];
}

__global__ void add_off_kernel(int* __restrict__ rp, const int* __restrict__ bsum,
                               int* __restrict__ cnt, int N){
  int i = blockIdx.x*256 + threadIdx.x;
  if (i < N){ rp[i+1] += bsum[i >> 10]; cnt[i] = 0; }
  if (i == 0) rp[0] = 0;
}

__global__ void fill_kernel(const int* __restrict__ ei, const int* __restrict__ rp,
                            int* __restrict__ cnt, int* __restrict__ csrc, int E){
  int e = blockIdx.x*256 + threadIdx.x;
  if (e < E){
    int s = ei[e]; int d = ei[E + e];
    int pos = rp[d] + atomicAdd(&cnt[d], 1);
    csrc[pos] = s;
  }
}

// ---------- GEMM: out[N,256] = A[N,256] @ W[256,256] (no bias) ----------
// Register-blocked LDS tiling: BM=BN=128, BK=16, 256 threads, 8x8 out/thread.

__global__ __launch_bounds__(256) void gemm_kernel(const float* __restrict__ A,
                                                   const float* __restrict__ W,
                                                   float* __restrict__ out, int N){
  __shared__ float As[16][132];   // As[k][m]  (transposed A tile)
  __shared__ float Bs[16][132];   // Bs[k][c]
  int tid = threadIdx.x;
  int tx = tid & 15, ty = tid >> 4;
  int r0 = blockIdx.x * 128;
  int c0 = blockIdx.y * 128;

  int am = tid >> 2;
  int ak = (tid & 3) << 2;
  int bk = tid >> 5;
  int bc = (tid & 31) << 2;

  int arow0 = min(r0 + am, N - 1);
  int arow1 = min(r0 + 64 + am, N - 1);

  float4 acc[2][2][4];
  #pragma unroll
  for (int a = 0; a < 2; a++)
    #pragma unroll
    for (int b = 0; b < 2; b++)
      #pragma unroll
      for (int i = 0; i < 4; i++)
        acc[a][b][i] = make_float4(0.f, 0.f, 0.f, 0.f);

  for (int kb = 0; kb < 256; kb += 16){
    float4 av0 = *(const float4*)&A[(size_t)arow0*256 + kb + ak];
    float4 av1 = *(const float4*)&A[(size_t)arow1*256 + kb + ak];
    As[ak+0][am]      = av0.x; As[ak+1][am]      = av0.y;
    As[ak+2][am]      = av0.z; As[ak+3][am]      = av0.w;
    As[ak+0][64+am]   = av1.x; As[ak+1][64+am]   = av1.y;
    As[ak+2][64+am]   = av1.z; As[ak+3][64+am]   = av1.w;
    float4 bv0 = *(const float4*)&W[(size_t)(kb + bk)*256 + c0 + bc];
    float4 bv1 = *(const float4*)&W[(size_t)(kb + bk + 8)*256 + c0 + bc];
    *(float4*)&Bs[bk][bc]     = bv0;
    *(float4*)&Bs[bk+8][bc]   = bv1;
    __syncthreads();

    #pragma unroll
    for (int k = 0; k < 16; k++){
      float4 a0 = *(const float4*)&As[k][ty*4];
      float4 a1 = *(const float4*)&As[k][64 + ty*4];
      float4 b0 = *(const float4*)&Bs[k][tx*4];
      float4 b1 = *(const float4*)&Bs[k][64 + tx*4];
      const float* ap0 = (const float*)&a0;
      const float* ap1 = (const float*)&a1;
      #pragma unroll
      for (int i = 0; i < 4; i++){
        float r0v = ap0[i], r1v = ap1[i];
        acc[0][0][i].x = fmaf(r0v, b0.x, acc[0][0][i].x);
        acc[0][0][i].y = fmaf(r0v, b0.y, acc[0][0][i].y);
        acc[0][0][i].z = fmaf(r0v, b0.z, acc[0][0][i].z);
        acc[0][0][i].w = fmaf(r0v, b0.w, acc[0][0][i].w);
        acc[0][1][i].x = fmaf(r0v, b1.x, acc[0][1][i].x);
        acc[0][1][i].y = fmaf(r0v, b1.y, acc[0][1][i].y);
        acc[0][1][i].z = fmaf(r0v, b1.z, acc[0][1][i].z);
        acc[0][1][i].w = fmaf(r0v, b1.w, acc[0][1][i].w);
        acc[1][0][i].x = fmaf(r1v, b0.x, acc[1][0][i].x);
        acc[1][0][i].y = fmaf(r1v, b0.y, acc[1][0][i].y);
        acc[1][0][i].z = fmaf(r1v, b0.z, acc[1][0][i].z);
        acc[1][0][i].w = fmaf(r1v, b0.w, acc[1][0][i].w);
        acc[1][1][i].x = fmaf(r1v, b1.x, acc[1][1][i].x);
        acc[1][1][i].y = fmaf(r1v, b1.y, acc[1][1][i].y);
        acc[1][1][i].z = fmaf(r1v, b1.z, acc[1][1][i].z);
        acc[1][1][i].w = fmaf(r1v, b1.w, acc[1][1][i].w);
      }
    }
    __syncthreads();
  }

  #pragma unroll
  for (int rb = 0; rb < 2; rb++){
    #pragma unroll
    for (int i = 0; i < 4; i++){
      int r = r0 + rb*64 + ty*4 + i;
      if (r < N){
        *(float4*)&out[(size_t)r*256 + c0 + tx*4]      = acc[rb][0][i];
        *(float4*)&out[(size_t)r*256 + c0 + 64 + tx*4] = acc[rb][1][i];
      }
    }
  }
}

// ---------- GCN aggregation ----------

__global__ __launch_bounds__(256) void agg_kernel(const float* __restrict__ xw,
                                                  const float* __restrict__ dis,
                                                  const int* __restrict__ rp,
                                                  const int* __restrict__ csrc,
                                                  const float* __restrict__ bias,
                                                  float* __restrict__ out, int N){
  int node = blockIdx.x*4 + (threadIdx.x >> 6);
  int lane = threadIdx.x & 63;
  if (node >= N) return;
  const float4* xw4 = (const float4*)xw;
  float di = dis[node];
  float4 a = xw4[(size_t)node*64 + lane];
  float sc = di * di;
  float4 acc;
  acc.x = a.x*sc; acc.y = a.y*sc; acc.z = a.z*sc; acc.w = a.w*sc;
  int e0 = rp[node], e1 = rp[node+1];
  for (int e = e0; e < e1; e++){
    int s = csrc[e];
    float cc = dis[s] * di;
    float4 v = xw4[(size_t)s*64 + lane];
    acc.x = fmaf(v.x, cc, acc.x);
    acc.y = fmaf(v.y, cc, acc.y);
    acc.z = fmaf(v.z, cc, acc.z);
    acc.w = fmaf(v.w, cc, acc.w);
  }
  const float4* b4 = (const float4*)bias;
  float4 b = b4[lane];
  acc.x = fmaxf(acc.x + b.x, 0.f);
  acc.y = fmaxf(acc.y + b.y, 0.f);
  acc.z = fmaxf(acc.z + b.z, 0.f);
  acc.w = fmaxf(acc.w + b.w, 0.f);
  ((float4*)out)[(size_t)node*64 + lane] = acc;
}

// ---------- mean pool ----------

__global__ void pool_kernel(const float* __restrict__ h, const int* __restrict__ ptr,
                            float* __restrict__ hp){
  int t = blockIdx.x; int part = blockIdx.y; int c = threadIdx.x;
  int s0 = ptr[t], s1 = ptr[t+1];
  int len = s1 - s0;
  int chunk = (len + 7) / 8;
  int r0 = s0 + part*chunk;
  int r1 = min(r0 + chunk, s1);
  float acc = 0.f;
  for (int r = r0; r < r1; r++) acc += h[(size_t)r*256 + c];
  if (r1 > r0) atomicAdd(&hp[t*256 + c], acc);
}

__global__ void hp_div_kernel(float* __restrict__ hp, const int* __restrict__ ptr){
  int t = blockIdx.x; int c = threadIdx.x;
  float cf = (float)max(ptr[t+1] - ptr[t], 1);
  hp[t*256 + c] /= cf;
}

// ---------- GX[t,g] = dot(hp[t], w_ih[g]) + b_ih[g] ----------

__global__ __launch_bounds__(768) void gx_kernel(const float* __restrict__ hp,
                                                 const float* __restrict__ wih,
                                                 const float* __restrict__ bih,
                                                 float* __restrict__ gx){
  __shared__ float xs[256];
  int t = blockIdx.x; int g = threadIdx.x;
  if (g < 256) xs[g] = hp[t*256 + g];
  __syncthreads();
  float acc = bih[g];
  const float* wr = wih + (size_t)g*256;
  #pragma unroll 4
  for (int k = 0; k < 256; k++) acc = fmaf(xs[k], wr[k], acc);
  gx[t*768 + g] = acc;
}

// ---------- sequential GRU: single block, 512 threads, w_hh register-resident f16 ----------
// thread (i = tid>>1, half = tid&1) owns rows i, i+256, i+512 of w_hh over k-slice
// [half*128, half*128+128). CRITICAL: the preload loop is FULLY unrolled so wr/wz/wn
// are only ever indexed by compile-time constants -> promoted to VGPRs (round-3's
// `#pragma unroll 8` left dynamic indices -> 384KB scratch spill, 752us).

__global__ __launch_bounds__(512, 2) void gru_kernel(const float* __restrict__ gx,
                                                     const float* __restrict__ whh,
                                                     const float* __restrict__ bhh,
                                                     const float* __restrict__ Wc,
                                                     const float* __restrict__ bc,
                                                     float* __restrict__ out){
  __shared__ _Float16 hh[256];
  __shared__ float hfin[256];
  int tid = threadIdx.x;
  int i = tid >> 1;        // gate index 0..255
  int half = tid & 1;      // k-half

  // preload weight slices into registers as f16 pairs (FULL unroll -> VGPRs)
  h2_t wr[64], wz[64], wn[64];
  {
    const float2* w2 = (const float2*)whh;
    size_t base = (size_t)half * 64;
    const float2* pr = w2 + (size_t)i*128       + base;
    const float2* pz = w2 + (size_t)(i+256)*128 + base;
    const float2* pn = w2 + (size_t)(i+512)*128 + base;
    #pragma unroll
    for (int k = 0; k < 64; k++){
      float2 a = pr[k];
      float2 b = pz[k];
      float2 c = pn[k];
      wr[k] = h2_t{(_Float16)a.x, (_Float16)a.y};
      wz[k] = h2_t{(_Float16)b.x, (_Float16)b.y};
      wn[k] = h2_t{(_Float16)c.x, (_Float16)c.y};
    }
  }
  float bR = bhh[i], bZ = bhh[i+256], bN = bhh[i+512];
  float h = 0.f;

  for (int t = 0; t < 64; t++){
    if (half == 0) hh[i] = (_Float16)h;
    __syncthreads();
    float gxr = gx[t*768 + i];
    float gxz = gx[t*768 + 256 + i];
    float gxn = gx[t*768 + 512 + i];
    const h2_t* hp2 = ((const h2_t*)hh) + half*64;
    float accR = 0.f, accZ = 0.f, accN = 0.f;
    #pragma unroll
    for (int k = 0; k < 64; k++){
      h2_t hv = hp2[k];
#ifdef HAS_FDOT2
      accR = __builtin_amdgcn_fdot2(hv, wr[k], accR, false);
      accZ = __builtin_amdgcn_fdot2(hv, wz[k], accZ, false);
      accN = __builtin_amdgcn_fdot2(hv, wn[k], accN, false);
#else
      accR = fmaf((float)hv.x, (float)wr[k].x, accR);
      accR = fmaf((float)hv.y, (float)wr[k].y, accR);
      accZ = fmaf((float)hv.x, (float)wz[k].x, accZ);
      accZ = fmaf((float)hv.y, (float)wz[k].y, accZ);
      accN = fmaf((float)hv.x, (float)wn[k].x, accN);
      accN = fmaf((float)hv.y, (float)wn[k].y, accN);
#endif
    }
    accR += __shfl_xor(accR, 1);
    accZ += __shfl_xor(accZ, 1);
    accN += __shfl_xor(accN, 1);
    // gates (both lanes compute identically; b_hh n-bias goes inside r*(.))
    float r = 1.f/(1.f + expf(-(gxr + accR + bR)));
    float z = 1.f/(1.f + expf(-(gxz + accZ + bZ)));
    float n = tanhf(gxn + r*(accN + bN));
    float hnew = (1.f - z)*n + z*h;
    __syncthreads();   // all reads of hh done before next-iter write
    h = hnew;
  }

  if (half == 0) hfin[i] = h;
  __syncthreads();
  if (tid < 16){
    float acc = bc[tid];
    const float* wrow = Wc + (size_t)tid*256;
    for (int k = 0; k < 256; k++) acc = fmaf(hfin[k], wrow[k], acc);
    out[tid] = acc;
  }
}

extern "C" void kernel_launch(void* const* d_in, const int* in_sizes, int n_in,
                              void* d_out, int out_size, void* d_ws, size_t ws_size,
                              hipStream_t stream){
  const float* x   = (const float*)d_in[0];
  const int*   ei  = (const int*)d_in[1];
  const int*   ptr = (const int*)d_in[2];
  const float* W1  = (const float*)d_in[3];
  const float* b1  = (const float*)d_in[4];
  const float* W2  = (const float*)d_in[5];
  const float* b2  = (const float*)d_in[6];
  const float* wih = (const float*)d_in[7];
  const float* whh = (const float*)d_in[8];
  const float* bih = (const float*)d_in[9];
  const float* bhh = (const float*)d_in[10];
  const float* Wc  = (const float*)d_in[11];
  const float* bc  = (const float*)d_in[12];
  float* outp = (float*)d_out;

  const int N = in_sizes[0] / 256;   // 100000
  const int E = in_sizes[1] / 2;     // 1600000

  char* w = (char*)d_ws;
  size_t off = 0;
  auto alloc = [&](size_t bytes){ void* p = w + off; off = align512(off + bytes); return p; };
  float* bufA = (float*)alloc((size_t)N*256*4);   // xw
  float* bufB = (float*)alloc((size_t)N*256*4);   // h (post-agg)
  float* dis  = (float*)alloc((size_t)N*4);
  int*   cnt  = (int*)  alloc((size_t)N*4);
  int*   rp   = (int*)  alloc((size_t)(N+1)*4);
  int*   bsum = (int*)  alloc(128*4);
  int*   csrc = (int*)  alloc((size_t)E*4);
  float* hp   = (float*)alloc((size_t)64*256*4);
  float* gxb  = (float*)alloc((size_t)64*768*4);
  (void)ws_size; (void)n_in; (void)out_size;

  hipMemsetAsync(cnt, 0, (size_t)N*4, stream);
  hipMemsetAsync(hp,  0, (size_t)64*256*4, stream);

  // CSR build + degree
  count_kernel<<<(E+255)/256, 256, 0, stream>>>(ei, cnt, E);
  dis_kernel<<<(N+255)/256, 256, 0, stream>>>(cnt, dis, N);
  int nb = (N + 1023) / 1024;
  scan_block_kernel<<<nb, 1024, 0, stream>>>(cnt, rp, bsum, N);
  scan_sums_kernel<<<1, 128, 0, stream>>>(bsum, nb);
  add_off_kernel<<<(N+255)/256, 256, 0, stream>>>(rp, bsum, cnt, N);
  fill_kernel<<<(E+255)/256, 256, 0, stream>>>(ei, rp, cnt, csrc, E);

  // GCN layer 1
  gemm_kernel<<<dim3((N+127)/128, 2), 256, 0, stream>>>(x, W1, bufA, N);
  agg_kernel<<<(N+3)/4, 256, 0, stream>>>(bufA, dis, rp, csrc, b1, bufB, N);
  // GCN layer 2
  gemm_kernel<<<dim3((N+127)/128, 2), 256, 0, stream>>>(bufB, W2, bufA, N);
  agg_kernel<<<(N+3)/4, 256, 0, stream>>>(bufA, dis, rp, csrc, b2, bufB, N);

  // pool + GRU + classifier
  pool_kernel<<<dim3(64, 8), 256, 0, stream>>>(bufB, ptr, hp);
  hp_div_kernel<<<64, 256, 0, stream>>>(hp, ptr);
  gx_kernel<<<64, 768, 0, stream>>>(hp, wih, bih, gxb);
  gru_kernel<<<1, 512, 0, stream>>>(gxb, whh, bhh, Wc, bc, outp);
}

// Round 5
// 1104.369 us; speedup vs baseline: 1.7653x; 1.1970x over previous
//
#include <hip/hip_runtime.h>
#include <hip/hip_bf16.h>
#include <math.h>

// Problem constants (fixed by reference): N=100000 nodes, E=1.6M edges, H=256, T=64.

static inline size_t align512(size_t x){ return (x + 511) & ~size_t(511); }

typedef _Float16 h2_t __attribute__((ext_vector_type(2)));
typedef unsigned short ushort_t;

#if defined(__has_builtin)
#if __has_builtin(__builtin_amdgcn_fdot2)
#define HAS_FDOT2 1
#endif
#endif

__device__ inline ushort_t f2bf(float f){
  unsigned u = __float_as_uint(f);
  unsigned r = u + 0x7FFFu + ((u >> 16) & 1u);   // RTNE
  return (ushort_t)(r >> 16);
}
__device__ inline float bf2f(ushort_t h){ return __uint_as_float(((unsigned)h) << 16); }

// ---------- CSR build ----------

__global__ void count_kernel(const int* __restrict__ ei, int* __restrict__ cnt, int E){
  int e = blockIdx.x*256 + threadIdx.x;
  if (e < E) atomicAdd(&cnt[ei[E + e]], 1);
}

__global__ void dis_kernel(const int* __restrict__ cnt, float* __restrict__ dis, int N){
  int i = blockIdx.x*256 + threadIdx.x;
  if (i < N) dis[i] = rsqrtf((float)cnt[i] + 1.0f);
}

__global__ void scan_block_kernel(const int* __restrict__ cnt, int* __restrict__ rp,
                                  int* __restrict__ bsum, int N){
  __shared__ int s[2][1024];
  int t = threadIdx.x; int i = blockIdx.x*1024 + t;
  int v = (i < N) ? cnt[i] : 0;
  int cur = 0; s[0][t] = v; __syncthreads();
  for (int off = 1; off < 1024; off <<= 1){
    int nxt = cur ^ 1;
    int val = s[cur][t];
    if (t >= off) val += s[cur][t - off];
    s[nxt][t] = val; cur = nxt; __syncthreads();
  }
  if (i < N) rp[i+1] = s[cur][t];
  if (t == 1023) bsum[blockIdx.x] = s[cur][1023];
}

__global__ void scan_sums_kernel(int* __restrict__ bsum, int nb){
  __shared__ int s[128];
  int t = threadIdx.x;
  if (t < nb) s[t] = bsum[t];
  __syncthreads();
  if (t == 0){ int acc = 0; for (int b = 0; b < nb; b++){ int v = s[b]; s[b] = acc; acc += v; } }
  __syncthreads();
  if (t < nb) bsum[t] = s[t];
}

__global__ void add_off_kernel(int* __restrict__ rp, const int* __restrict__ bsum,
                               int* __restrict__ cnt, int N){
  int i = blockIdx.x*256 + threadIdx.x;
  if (i < N){ rp[i+1] += bsum[i >> 10]; cnt[i] = 0; }
  if (i == 0) rp[0] = 0;
}

__global__ void fill_kernel(const int* __restrict__ ei, const int* __restrict__ rp,
                            int* __restrict__ cnt, int* __restrict__ csrc, int E){
  int e = blockIdx.x*256 + threadIdx.x;
  if (e < E){
    int s = ei[e]; int d = ei[E + e];
    int pos = rp[d] + atomicAdd(&cnt[d], 1);
    csrc[pos] = s;
  }
}

// ---------- GEMM: out[N,256](bf16) = A[N,256] @ W[256,256] ----------
// Register-blocked LDS tiling: BM=BN=128, BK=16, 256 threads, 8x8 out/thread.
// A is fp32 (layer 1: x) or bf16 (layer 2: h1); compute fp32; out stored bf16.

template<bool A_BF16>
__global__ __launch_bounds__(256) void gemm_kernel(const void* __restrict__ Ap,
                                                   const float* __restrict__ W,
                                                   ushort_t* __restrict__ out, int N){
  __shared__ float As[16][132];   // As[k][m]  (transposed A tile)
  __shared__ float Bs[16][132];   // Bs[k][c]
  int tid = threadIdx.x;
  int tx = tid & 15, ty = tid >> 4;
  int r0 = blockIdx.x * 128;
  int c0 = blockIdx.y * 128;

  int am = tid >> 2;
  int ak = (tid & 3) << 2;
  int bk = tid >> 5;
  int bc = (tid & 31) << 2;

  int arow0 = min(r0 + am, N - 1);
  int arow1 = min(r0 + 64 + am, N - 1);

  float4 acc[2][2][4];
  #pragma unroll
  for (int a = 0; a < 2; a++)
    #pragma unroll
    for (int b = 0; b < 2; b++)
      #pragma unroll
      for (int i = 0; i < 4; i++)
        acc[a][b][i] = make_float4(0.f, 0.f, 0.f, 0.f);

  for (int kb = 0; kb < 256; kb += 16){
    float4 av0, av1;
    if constexpr (A_BF16){
      const ushort_t* A = (const ushort_t*)Ap;
      ushort4 u0 = *(const ushort4*)&A[(size_t)arow0*256 + kb + ak];
      ushort4 u1 = *(const ushort4*)&A[(size_t)arow1*256 + kb + ak];
      av0 = make_float4(bf2f(u0.x), bf2f(u0.y), bf2f(u0.z), bf2f(u0.w));
      av1 = make_float4(bf2f(u1.x), bf2f(u1.y), bf2f(u1.z), bf2f(u1.w));
    } else {
      const float* A = (const float*)Ap;
      av0 = *(const float4*)&A[(size_t)arow0*256 + kb + ak];
      av1 = *(const float4*)&A[(size_t)arow1*256 + kb + ak];
    }
    As[ak+0][am]      = av0.x; As[ak+1][am]      = av0.y;
    As[ak+2][am]      = av0.z; As[ak+3][am]      = av0.w;
    As[ak+0][64+am]   = av1.x; As[ak+1][64+am]   = av1.y;
    As[ak+2][64+am]   = av1.z; As[ak+3][64+am]   = av1.w;
    float4 bv0 = *(const float4*)&W[(size_t)(kb + bk)*256 + c0 + bc];
    float4 bv1 = *(const float4*)&W[(size_t)(kb + bk + 8)*256 + c0 + bc];
    *(float4*)&Bs[bk][bc]     = bv0;
    *(float4*)&Bs[bk+8][bc]   = bv1;
    __syncthreads();

    #pragma unroll
    for (int k = 0; k < 16; k++){
      float4 a0 = *(const float4*)&As[k][ty*4];
      float4 a1 = *(const float4*)&As[k][64 + ty*4];
      float4 b0 = *(const float4*)&Bs[k][tx*4];
      float4 b1 = *(const float4*)&Bs[k][64 + tx*4];
      const float* ap0 = (const float*)&a0;
      const float* ap1 = (const float*)&a1;
      #pragma unroll
      for (int i = 0; i < 4; i++){
        float r0v = ap0[i], r1v = ap1[i];
        acc[0][0][i].x = fmaf(r0v, b0.x, acc[0][0][i].x);
        acc[0][0][i].y = fmaf(r0v, b0.y, acc[0][0][i].y);
        acc[0][0][i].z = fmaf(r0v, b0.z, acc[0][0][i].z);
        acc[0][0][i].w = fmaf(r0v, b0.w, acc[0][0][i].w);
        acc[0][1][i].x = fmaf(r0v, b1.x, acc[0][1][i].x);
        acc[0][1][i].y = fmaf(r0v, b1.y, acc[0][1][i].y);
        acc[0][1][i].z = fmaf(r0v, b1.z, acc[0][1][i].z);
        acc[0][1][i].w = fmaf(r0v, b1.w, acc[0][1][i].w);
        acc[1][0][i].x = fmaf(r1v, b0.x, acc[1][0][i].x);
        acc[1][0][i].y = fmaf(r1v, b0.y, acc[1][0][i].y);
        acc[1][0][i].z = fmaf(r1v, b0.z, acc[1][0][i].z);
        acc[1][0][i].w = fmaf(r1v, b0.w, acc[1][0][i].w);
        acc[1][1][i].x = fmaf(r1v, b1.x, acc[1][1][i].x);
        acc[1][1][i].y = fmaf(r1v, b1.y, acc[1][1][i].y);
        acc[1][1][i].z = fmaf(r1v, b1.z, acc[1][1][i].z);
        acc[1][1][i].w = fmaf(r1v, b1.w, acc[1][1][i].w);
      }
    }
    __syncthreads();
  }

  #pragma unroll
  for (int rb = 0; rb < 2; rb++){
    #pragma unroll
    for (int i = 0; i < 4; i++){
      int r = r0 + rb*64 + ty*4 + i;
      if (r < N){
        float4 v0 = acc[rb][0][i];
        float4 v1 = acc[rb][1][i];
        ushort4 s0, s1;
        s0.x = f2bf(v0.x); s0.y = f2bf(v0.y); s0.z = f2bf(v0.z); s0.w = f2bf(v0.w);
        s1.x = f2bf(v1.x); s1.y = f2bf(v1.y); s1.z = f2bf(v1.z); s1.w = f2bf(v1.w);
        *(ushort4*)&out[(size_t)r*256 + c0 + tx*4]      = s0;
        *(ushort4*)&out[(size_t)r*256 + c0 + 64 + tx*4] = s1;
      }
    }
  }
}

// ---------- GCN aggregation (bf16 features): half-wave (32 lanes) per node,
// 8 cols/lane as one 16B uint4 load -> halves both bytes AND requests per edge.

__global__ __launch_bounds__(256) void agg_kernel(const ushort_t* __restrict__ xw,
                                                  const float* __restrict__ dis,
                                                  const int* __restrict__ rp,
                                                  const int* __restrict__ csrc,
                                                  const float* __restrict__ bias,
                                                  ushort_t* __restrict__ out, int N){
  int node = blockIdx.x*8 + (threadIdx.x >> 5);
  int lane = threadIdx.x & 31;
  if (node >= N) return;
  const uint4* xw4 = (const uint4*)xw;     // 16B = 8 bf16; row = 32 uint4s
  float di = dis[node];
  float sc = di * di;
  float acc[8];
  {
    uint4 a = xw4[(size_t)node*32 + lane];
    acc[0] = __uint_as_float(a.x << 16) * sc;
    acc[1] = __uint_as_float(a.x & 0xFFFF0000u) * sc;
    acc[2] = __uint_as_float(a.y << 16) * sc;
    acc[3] = __uint_as_float(a.y & 0xFFFF0000u) * sc;
    acc[4] = __uint_as_float(a.z << 16) * sc;
    acc[5] = __uint_as_float(a.z & 0xFFFF0000u) * sc;
    acc[6] = __uint_as_float(a.w << 16) * sc;
    acc[7] = __uint_as_float(a.w & 0xFFFF0000u) * sc;
  }
  int e0 = rp[node], e1 = rp[node+1];
  for (int e = e0; e < e1; e++){
    int s = csrc[e];
    float cc = dis[s] * di;
    uint4 v = xw4[(size_t)s*32 + lane];
    acc[0] = fmaf(__uint_as_float(v.x << 16),          cc, acc[0]);
    acc[1] = fmaf(__uint_as_float(v.x & 0xFFFF0000u),  cc, acc[1]);
    acc[2] = fmaf(__uint_as_float(v.y << 16),          cc, acc[2]);
    acc[3] = fmaf(__uint_as_float(v.y & 0xFFFF0000u),  cc, acc[3]);
    acc[4] = fmaf(__uint_as_float(v.z << 16),          cc, acc[4]);
    acc[5] = fmaf(__uint_as_float(v.z & 0xFFFF0000u),  cc, acc[5]);
    acc[6] = fmaf(__uint_as_float(v.w << 16),          cc, acc[6]);
    acc[7] = fmaf(__uint_as_float(v.w & 0xFFFF0000u),  cc, acc[7]);
  }
  const float4* b4 = (const float4*)bias;   // bias fp32, cols lane*8..lane*8+7
  float4 bA = b4[lane*2], bB = b4[lane*2+1];
  acc[0] = fmaxf(acc[0] + bA.x, 0.f);
  acc[1] = fmaxf(acc[1] + bA.y, 0.f);
  acc[2] = fmaxf(acc[2] + bA.z, 0.f);
  acc[3] = fmaxf(acc[3] + bA.w, 0.f);
  acc[4] = fmaxf(acc[4] + bB.x, 0.f);
  acc[5] = fmaxf(acc[5] + bB.y, 0.f);
  acc[6] = fmaxf(acc[6] + bB.z, 0.f);
  acc[7] = fmaxf(acc[7] + bB.w, 0.f);
  uint4 o;
  o.x = ((unsigned)f2bf(acc[1]) << 16) | f2bf(acc[0]);
  o.y = ((unsigned)f2bf(acc[3]) << 16) | f2bf(acc[2]);
  o.z = ((unsigned)f2bf(acc[5]) << 16) | f2bf(acc[4]);
  o.w = ((unsigned)f2bf(acc[7]) << 16) | f2bf(acc[6]);
  ((uint4*)out)[(size_t)node*32 + lane] = o;
}

// ---------- mean pool (bf16 input, fp32 accumulate) ----------

__global__ void pool_kernel(const ushort_t* __restrict__ h, const int* __restrict__ ptr,
                            float* __restrict__ hp){
  int t = blockIdx.x; int part = blockIdx.y; int c = threadIdx.x;
  int s0 = ptr[t], s1 = ptr[t+1];
  int len = s1 - s0;
  int chunk = (len + 7) / 8;
  int r0 = s0 + part*chunk;
  int r1 = min(r0 + chunk, s1);
  float acc = 0.f;
  for (int r = r0; r < r1; r++) acc += bf2f(h[(size_t)r*256 + c]);
  if (r1 > r0) atomicAdd(&hp[t*256 + c], acc);
}

__global__ void hp_div_kernel(float* __restrict__ hp, const int* __restrict__ ptr){
  int t = blockIdx.x; int c = threadIdx.x;
  float cf = (float)max(ptr[t+1] - ptr[t], 1);
  hp[t*256 + c] /= cf;
}

// ---------- GX[t,g] = dot(hp[t], w_ih[g]) + b_ih[g] ----------

__global__ __launch_bounds__(768) void gx_kernel(const float* __restrict__ hp,
                                                 const float* __restrict__ wih,
                                                 const float* __restrict__ bih,
                                                 float* __restrict__ gx){
  __shared__ float xs[256];
  int t = blockIdx.x; int g = threadIdx.x;
  if (g < 256) xs[g] = hp[t*256 + g];
  __syncthreads();
  float acc = bih[g];
  const float* wr = wih + (size_t)g*256;
  #pragma unroll 4
  for (int k = 0; k < 256; k++) acc = fmaf(xs[k], wr[k], acc);
  gx[t*768 + g] = acc;
}

// ---------- sequential GRU: single block, 512 threads, w_hh register-resident f16 ----------
// FULL unroll on the preload so wr/wz/wn promote to VGPRs (partial unroll -> scratch spill).

__global__ __launch_bounds__(512, 2) void gru_kernel(const float* __restrict__ gx,
                                                     const float* __restrict__ whh,
                                                     const float* __restrict__ bhh,
                                                     const float* __restrict__ Wc,
                                                     const float* __restrict__ bc,
                                                     float* __restrict__ out){
  __shared__ _Float16 hh[256];
  __shared__ float hfin[256];
  int tid = threadIdx.x;
  int i = tid >> 1;        // gate index 0..255
  int half = tid & 1;      // k-half

  h2_t wr[64], wz[64], wn[64];
  {
    const float2* w2 = (const float2*)whh;
    size_t base = (size_t)half * 64;
    const float2* pr = w2 + (size_t)i*128       + base;
    const float2* pz = w2 + (size_t)(i+256)*128 + base;
    const float2* pn = w2 + (size_t)(i+512)*128 + base;
    #pragma unroll
    for (int k = 0; k < 64; k++){
      float2 a = pr[k];
      float2 b = pz[k];
      float2 c = pn[k];
      wr[k] = h2_t{(_Float16)a.x, (_Float16)a.y};
      wz[k] = h2_t{(_Float16)b.x, (_Float16)b.y};
      wn[k] = h2_t{(_Float16)c.x, (_Float16)c.y};
    }
  }
  float bR = bhh[i], bZ = bhh[i+256], bN = bhh[i+512];
  float h = 0.f;

  for (int t = 0; t < 64; t++){
    if (half == 0) hh[i] = (_Float16)h;
    __syncthreads();
    float gxr = gx[t*768 + i];
    float gxz = gx[t*768 + 256 + i];
    float gxn = gx[t*768 + 512 + i];
    const h2_t* hp2 = ((const h2_t*)hh) + half*64;
    float accR = 0.f, accZ = 0.f, accN = 0.f;
    #pragma unroll
    for (int k = 0; k < 64; k++){
      h2_t hv = hp2[k];
#ifdef HAS_FDOT2
      accR = __builtin_amdgcn_fdot2(hv, wr[k], accR, false);
      accZ = __builtin_amdgcn_fdot2(hv, wz[k], accZ, false);
      accN = __builtin_amdgcn_fdot2(hv, wn[k], accN, false);
#else
      accR = fmaf((float)hv.x, (float)wr[k].x, accR);
      accR = fmaf((float)hv.y, (float)wr[k].y, accR);
      accZ = fmaf((float)hv.x, (float)wz[k].x, accZ);
      accZ = fmaf((float)hv.y, (float)wz[k].y, accZ);
      accN = fmaf((float)hv.x, (float)wn[k].x, accN);
      accN = fmaf((float)hv.y, (float)wn[k].y, accN);
#endif
    }
    accR += __shfl_xor(accR, 1);
    accZ += __shfl_xor(accZ, 1);
    accN += __shfl_xor(accN, 1);
    float r = 1.f/(1.f + expf(-(gxr + accR + bR)));
    float z = 1.f/(1.f + expf(-(gxz + accZ + bZ)));
    float n = tanhf(gxn + r*(accN + bN));
    float hnew = (1.f - z)*n + z*h;
    __syncthreads();
    h = hnew;
  }

  if (half == 0) hfin[i] = h;
  __syncthreads();
  if (tid < 16){
    float acc = bc[tid];
    const float* wrow = Wc + (size_t)tid*256;
    for (int k = 0; k < 256; k++) acc = fmaf(hfin[k], wrow[k], acc);
    out[tid] = acc;
  }
}

extern "C" void kernel_launch(void* const* d_in, const int* in_sizes, int n_in,
                              void* d_out, int out_size, void* d_ws, size_t ws_size,
                              hipStream_t stream){
  const float* x   = (const float*)d_in[0];
  const int*   ei  = (const int*)d_in[1];
  const int*   ptr = (const int*)d_in[2];
  const float* W1  = (const float*)d_in[3];
  const float* b1  = (const float*)d_in[4];
  const float* W2  = (const float*)d_in[5];
  const float* b2  = (const float*)d_in[6];
  const float* wih = (const float*)d_in[7];
  const float* whh = (const float*)d_in[8];
  const float* bih = (const float*)d_in[9];
  const float* bhh = (const float*)d_in[10];
  const float* Wc  = (const float*)d_in[11];
  const float* bc  = (const float*)d_in[12];
  float* outp = (float*)d_out;

  const int N = in_sizes[0] / 256;   // 100000
  const int E = in_sizes[1] / 2;     // 1600000

  char* w = (char*)d_ws;
  size_t off = 0;
  auto alloc = [&](size_t bytes){ void* p = w + off; off = align512(off + bytes); return p; };
  ushort_t* bufA = (ushort_t*)alloc((size_t)N*256*2);   // xw  (bf16)
  ushort_t* bufB = (ushort_t*)alloc((size_t)N*256*2);   // h   (bf16)
  float* dis  = (float*)alloc((size_t)N*4);
  int*   cnt  = (int*)  alloc((size_t)N*4);
  int*   rp   = (int*)  alloc((size_t)(N+1)*4);
  int*   bsum = (int*)  alloc(128*4);
  int*   csrc = (int*)  alloc((size_t)E*4);
  float* hp   = (float*)alloc((size_t)64*256*4);
  float* gxb  = (float*)alloc((size_t)64*768*4);
  (void)ws_size; (void)n_in; (void)out_size;

  hipMemsetAsync(cnt, 0, (size_t)N*4, stream);
  hipMemsetAsync(hp,  0, (size_t)64*256*4, stream);

  // CSR build + degree
  count_kernel<<<(E+255)/256, 256, 0, stream>>>(ei, cnt, E);
  dis_kernel<<<(N+255)/256, 256, 0, stream>>>(cnt, dis, N);
  int nb = (N + 1023) / 1024;
  scan_block_kernel<<<nb, 1024, 0, stream>>>(cnt, rp, bsum, N);
  scan_sums_kernel<<<1, 128, 0, stream>>>(bsum, nb);
  add_off_kernel<<<(N+255)/256, 256, 0, stream>>>(rp, bsum, cnt, N);
  fill_kernel<<<(E+255)/256, 256, 0, stream>>>(ei, rp, cnt, csrc, E);

  // GCN layer 1
  gemm_kernel<false><<<dim3((N+127)/128, 2), 256, 0, stream>>>(x, W1, bufA, N);
  agg_kernel<<<(N+7)/8, 256, 0, stream>>>(bufA, dis, rp, csrc, b1, bufB, N);
  // GCN layer 2
  gemm_kernel<true><<<dim3((N+127)/128, 2), 256, 0, stream>>>(bufB, W2, bufA, N);
  agg_kernel<<<(N+7)/8, 256, 0, stream>>>(bufA, dis, rp, csrc, b2, bufB, N);

  // pool + GRU + classifier
  pool_kernel<<<dim3(64, 8), 256, 0, stream>>>(bufB, ptr, hp);
  hp_div_kernel<<<64, 256, 0, stream>>>(hp, ptr);
  gx_kernel<<<64, 768, 0, stream>>>(hp, wih, bih, gxb);
  gru_kernel<<<1, 512, 0, stream>>>(gxb, whh, bhh, Wc, bc, outp);
}

// Round 6
// 906.302 us; speedup vs baseline: 2.1511x; 1.2185x over previous
//
#include <hip/hip_runtime.h>
#include <hip/hip_bf16.h>
#include <math.h>

// Problem constants (fixed by reference): N=100000 nodes, E=1.6M edges, H=256, T=64.

static inline size_t align512(size_t x){ return (x + 511) & ~size_t(511); }

typedef _Float16 h2_t __attribute__((ext_vector_type(2)));
typedef unsigned short ushort_t;
typedef short bf16x8 __attribute__((ext_vector_type(8)));   // 8 bf16 = 4 VGPRs (MFMA A/B frag)
typedef float f32x4 __attribute__((ext_vector_type(4)));    // MFMA C/D frag

#if defined(__has_builtin)
#if __has_builtin(__builtin_amdgcn_fdot2)
#define HAS_FDOT2 1
#endif
#endif

__device__ inline ushort_t f2bf(float f){
  unsigned u = __float_as_uint(f);
  unsigned r = u + 0x7FFFu + ((u >> 16) & 1u);   // RTNE
  return (ushort_t)(r >> 16);
}
__device__ inline float bf2f(ushort_t h){ return __uint_as_float(((unsigned)h) << 16); }
__device__ inline unsigned pk2bf(float lo, float hi){
  return ((unsigned)f2bf(hi) << 16) | (unsigned)f2bf(lo);
}
__device__ inline bf16x8 as_bf16x8(uint4 u){
  union { uint4 u4; bf16x8 b; } c; c.u4 = u; return c.b;
}

// ---------- CSR build ----------

__global__ void count_kernel(const int* __restrict__ ei, int* __restrict__ cnt, int E){
  int e = blockIdx.x*256 + threadIdx.x;
  if (e < E) atomicAdd(&cnt[ei[E + e]], 1);
}

__global__ void dis_kernel(const int* __restrict__ cnt, float* __restrict__ dis, int N){
  int i = blockIdx.x*256 + threadIdx.x;
  if (i < N) dis[i] = rsqrtf((float)cnt[i] + 1.0f);
}

__global__ void scan_block_kernel(const int* __restrict__ cnt, int* __restrict__ rp,
                                  int* __restrict__ bsum, int N){
  __shared__ int s[2][1024];
  int t = threadIdx.x; int i = blockIdx.x*1024 + t;
  int v = (i < N) ? cnt[i] : 0;
  int cur = 0; s[0][t] = v; __syncthreads();
  for (int off = 1; off < 1024; off <<= 1){
    int nxt = cur ^ 1;
    int val = s[cur][t];
    if (t >= off) val += s[cur][t - off];
    s[nxt][t] = val; cur = nxt; __syncthreads();
  }
  if (i < N) rp[i+1] = s[cur][t];
  if (t == 1023) bsum[blockIdx.x] = s[cur][1023];
}

__global__ void scan_sums_kernel(int* __restrict__ bsum, int nb){
  __shared__ int s[128];
  int t = threadIdx.x;
  if (t < nb) s[t] = bsum[t];
  __syncthreads();
  if (t == 0){ int acc = 0; for (int b = 0; b < nb; b++){ int v = s[b]; s[b] = acc; acc += v; } }
  __syncthreads();
  if (t < nb) bsum[t] = s[t];
}

__global__ void add_off_kernel(int* __restrict__ rp, const int* __restrict__ bsum,
                               int* __restrict__ cnt, int N){
  int i = blockIdx.x*256 + threadIdx.x;
  if (i < N){ rp[i+1] += bsum[i >> 10]; cnt[i] = 0; }
  if (i == 0) rp[0] = 0;
}

__global__ void fill_kernel(const int* __restrict__ ei, const int* __restrict__ rp,
                            int* __restrict__ cnt, int* __restrict__ csrc, int E){
  int e = blockIdx.x*256 + threadIdx.x;
  if (e < E){
    int s = ei[e]; int d = ei[E + e];
    int pos = rp[d] + atomicAdd(&cnt[d], 1);
    csrc[pos] = s;
  }
}

// ---------- pack W (256x256 fp32 [k][n]) into MFMA B-fragment order (bf16) ----------
// flat uint4 index = (((cb*2+wc)*4+ct)*8 + q)*64 + lane
// holds B[k = q*32 + (lane>>4)*8 + j][n = (cb*128+wc*64+ct*16) + (lane&15)], j=0..7.

__global__ void packW_kernel(const float* __restrict__ W, uint4* __restrict__ Wp){
  int idx = blockIdx.x*256 + threadIdx.x;    // 0..8191
  int lane = idx & 63;
  int blk  = idx >> 6;                        // 0..127
  int q    = blk & 7;
  int t16  = blk >> 3;                        // 0..15 (16-col group)
  int n = t16*16 + (lane & 15);
  int k = q*32 + (lane >> 4)*8;
  uint4 v;
  v.x = pk2bf(W[(size_t)(k+0)*256 + n], W[(size_t)(k+1)*256 + n]);
  v.y = pk2bf(W[(size_t)(k+2)*256 + n], W[(size_t)(k+3)*256 + n]);
  v.z = pk2bf(W[(size_t)(k+4)*256 + n], W[(size_t)(k+5)*256 + n]);
  v.w = pk2bf(W[(size_t)(k+6)*256 + n], W[(size_t)(k+7)*256 + n]);
  Wp[idx] = v;
}

// ---------- MFMA GEMM: out[N,256](bf16) = A[N,256] @ W[256,256] ----------
// 128x128 tile, 4 waves (2x2), each wave 64x64 via 4x4 tiles of 16x16x32 MFMA.
// B register-resident (128 VGPRs, loaded once from packed Wp). A double-buffered
// in LDS (pad stride 40 ushort -> 2-way banks, free). K fully unrolled (8x32).

template<bool A_BF16>
__global__ __launch_bounds__(256, 2) void gemm_mfma(const void* __restrict__ Ap,
                                                    const uint4* __restrict__ Wp,
                                                    ushort_t* __restrict__ out, int N){
  __shared__ __align__(16) ushort_t As[2][128][40];
  int tid  = threadIdx.x;
  int lane = tid & 63;
  int wave = tid >> 6;
  int wr = wave >> 1, wc = wave & 1;
  int quad = lane >> 4;
  int l15  = lane & 15;
  int r0 = blockIdx.x * 128;
  int cb = blockIdx.y;

  // B fragments: [ct][q], register-resident
  uint4 bfr[4][8];
  {
    const uint4* wpb = Wp + (size_t)(cb*2 + wc) * 2048;
    #pragma unroll
    for (int ct = 0; ct < 4; ct++)
      #pragma unroll
      for (int q = 0; q < 8; q++)
        bfr[ct][q] = wpb[(ct*8 + q)*64 + lane];
  }

  f32x4 acc[4][4];
  #pragma unroll
  for (int rt = 0; rt < 4; rt++)
    #pragma unroll
    for (int ct = 0; ct < 4; ct++)
      acc[rt][ct] = f32x4{0.f, 0.f, 0.f, 0.f};

  // staging indices: 2 threads per row, 16 bf16 (32B) each
  int srow = tid >> 1;
  int shalf = tid & 1;
  int grow = min(r0 + srow, N - 1);

  auto load_stage = [&](int it, uint4& v0, uint4& v1){
    int k0 = it*32 + shalf*16;
    if constexpr (A_BF16){
      const ushort_t* Ab = (const ushort_t*)Ap;
      const uint4* ga = (const uint4*)(Ab + (size_t)grow*256 + k0);
      v0 = ga[0]; v1 = ga[1];
    } else {
      const float* Af = (const float*)Ap;
      const float4* ga = (const float4*)(Af + (size_t)grow*256 + k0);
      float4 f0 = ga[0], f1 = ga[1], f2 = ga[2], f3 = ga[3];
      v0.x = pk2bf(f0.x, f0.y); v0.y = pk2bf(f0.z, f0.w);
      v0.z = pk2bf(f1.x, f1.y); v0.w = pk2bf(f1.z, f1.w);
      v1.x = pk2bf(f2.x, f2.y); v1.y = pk2bf(f2.z, f2.w);
      v1.z = pk2bf(f3.x, f3.y); v1.w = pk2bf(f3.z, f3.w);
    }
  };
  auto write_stage = [&](int b, uint4 v0, uint4 v1){
    *(uint4*)&As[b][srow][shalf*16]     = v0;
    *(uint4*)&As[b][srow][shalf*16 + 8] = v1;
  };

  {
    uint4 v0, v1;
    load_stage(0, v0, v1);
    write_stage(0, v0, v1);
  }
  __syncthreads();

  #pragma unroll
  for (int it = 0; it < 8; it++){
    const int b = it & 1;
    uint4 n0, n1;
    if (it < 7) load_stage(it + 1, n0, n1);
    #pragma unroll
    for (int rt = 0; rt < 4; rt++){
      int arow = wr*64 + rt*16 + l15;
      uint4 av = *(const uint4*)&As[b][arow][quad*8];
      bf16x8 af = as_bf16x8(av);
      #pragma unroll
      for (int ct = 0; ct < 4; ct++)
        acc[rt][ct] = __builtin_amdgcn_mfma_f32_16x16x32_bf16(
            af, as_bf16x8(bfr[ct][it]), acc[rt][ct], 0, 0, 0);
    }
    if (it < 7){
      write_stage(b ^ 1, n0, n1);
      __syncthreads();
    }
  }

  // store C (bf16): row = r0+wr*64+rt*16+quad*4+g, col = cb*128+wc*64+ct*16+l15
  int crow0 = r0 + wr*64 + quad*4;
  int ccol0 = cb*128 + wc*64 + l15;
  #pragma unroll
  for (int rt = 0; rt < 4; rt++){
    #pragma unroll
    for (int g = 0; g < 4; g++){
      int row = crow0 + rt*16 + g;
      if (row < N){
        #pragma unroll
        for (int ct = 0; ct < 4; ct++)
          out[(size_t)row*256 + ccol0 + ct*16] = f2bf(acc[rt][ct][g]);
      }
    }
  }
}

// ---------- GCN aggregation (bf16 features): half-wave (32 lanes) per node,
// 8 cols/lane as one 16B uint4 load.

__global__ __launch_bounds__(256) void agg_kernel(const ushort_t* __restrict__ xw,
                                                  const float* __restrict__ dis,
                                                  const int* __restrict__ rp,
                                                  const int* __restrict__ csrc,
                                                  const float* __restrict__ bias,
                                                  ushort_t* __restrict__ out, int N){
  int node = blockIdx.x*8 + (threadIdx.x >> 5);
  int lane = threadIdx.x & 31;
  if (node >= N) return;
  const uint4* xw4 = (const uint4*)xw;     // 16B = 8 bf16; row = 32 uint4s
  float di = dis[node];
  float sc = di * di;
  float acc[8];
  {
    uint4 a = xw4[(size_t)node*32 + lane];
    acc[0] = __uint_as_float(a.x << 16) * sc;
    acc[1] = __uint_as_float(a.x & 0xFFFF0000u) * sc;
    acc[2] = __uint_as_float(a.y << 16) * sc;
    acc[3] = __uint_as_float(a.y & 0xFFFF0000u) * sc;
    acc[4] = __uint_as_float(a.z << 16) * sc;
    acc[5] = __uint_as_float(a.z & 0xFFFF0000u) * sc;
    acc[6] = __uint_as_float(a.w << 16) * sc;
    acc[7] = __uint_as_float(a.w & 0xFFFF0000u) * sc;
  }
  int e0 = rp[node], e1 = rp[node+1];
  for (int e = e0; e < e1; e++){
    int s = csrc[e];
    float cc = dis[s] * di;
    uint4 v = xw4[(size_t)s*32 + lane];
    acc[0] = fmaf(__uint_as_float(v.x << 16),          cc, acc[0]);
    acc[1] = fmaf(__uint_as_float(v.x & 0xFFFF0000u),  cc, acc[1]);
    acc[2] = fmaf(__uint_as_float(v.y << 16),          cc, acc[2]);
    acc[3] = fmaf(__uint_as_float(v.y & 0xFFFF0000u),  cc, acc[3]);
    acc[4] = fmaf(__uint_as_float(v.z << 16),          cc, acc[4]);
    acc[5] = fmaf(__uint_as_float(v.z & 0xFFFF0000u),  cc, acc[5]);
    acc[6] = fmaf(__uint_as_float(v.w << 16),          cc, acc[6]);
    acc[7] = fmaf(__uint_as_float(v.w & 0xFFFF0000u),  cc, acc[7]);
  }
  const float4* b4 = (const float4*)bias;
  float4 bA = b4[lane*2], bB = b4[lane*2+1];
  acc[0] = fmaxf(acc[0] + bA.x, 0.f);
  acc[1] = fmaxf(acc[1] + bA.y, 0.f);
  acc[2] = fmaxf(acc[2] + bA.z, 0.f);
  acc[3] = fmaxf(acc[3] + bA.w, 0.f);
  acc[4] = fmaxf(acc[4] + bB.x, 0.f);
  acc[5] = fmaxf(acc[5] + bB.y, 0.f);
  acc[6] = fmaxf(acc[6] + bB.z, 0.f);
  acc[7] = fmaxf(acc[7] + bB.w, 0.f);
  uint4 o;
  o.x = ((unsigned)f2bf(acc[1]) << 16) | f2bf(acc[0]);
  o.y = ((unsigned)f2bf(acc[3]) << 16) | f2bf(acc[2]);
  o.z = ((unsigned)f2bf(acc[5]) << 16) | f2bf(acc[4]);
  o.w = ((unsigned)f2bf(acc[7]) << 16) | f2bf(acc[6]);
  ((uint4*)out)[(size_t)node*32 + lane] = o;
}

// ---------- mean pool (bf16 input, fp32 accumulate) ----------

__global__ void pool_kernel(const ushort_t* __restrict__ h, const int* __restrict__ ptr,
                            float* __restrict__ hp){
  int t = blockIdx.x; int part = blockIdx.y; int c = threadIdx.x;
  int s0 = ptr[t], s1 = ptr[t+1];
  int len = s1 - s0;
  int chunk = (len + 7) / 8;
  int r0 = s0 + part*chunk;
  int r1 = min(r0 + chunk, s1);
  float acc = 0.f;
  for (int r = r0; r < r1; r++) acc += bf2f(h[(size_t)r*256 + c]);
  if (r1 > r0) atomicAdd(&hp[t*256 + c], acc);
}

__global__ void hp_div_kernel(float* __restrict__ hp, const int* __restrict__ ptr){
  int t = blockIdx.x; int c = threadIdx.x;
  float cf = (float)max(ptr[t+1] - ptr[t], 1);
  hp[t*256 + c] /= cf;
}

// ---------- GX[t,g] = dot(hp[t], w_ih[g]) + b_ih[g] ----------

__global__ __launch_bounds__(768) void gx_kernel(const float* __restrict__ hp,
                                                 const float* __restrict__ wih,
                                                 const float* __restrict__ bih,
                                                 float* __restrict__ gx){
  __shared__ float xs[256];
  int t = blockIdx.x; int g = threadIdx.x;
  if (g < 256) xs[g] = hp[t*256 + g];
  __syncthreads();
  float acc = bih[g];
  const float* wr = wih + (size_t)g*256;
  #pragma unroll 4
  for (int k = 0; k < 256; k++) acc = fmaf(xs[k], wr[k], acc);
  gx[t*768 + g] = acc;
}

// ---------- sequential GRU: single block, 512 threads, w_hh register-resident f16 ----------
// FULL unroll on the preload so wr/wz/wn promote to VGPRs (partial unroll -> scratch spill).

__global__ __launch_bounds__(512, 2) void gru_kernel(const float* __restrict__ gx,
                                                     const float* __restrict__ whh,
                                                     const float* __restrict__ bhh,
                                                     const float* __restrict__ Wc,
                                                     const float* __restrict__ bc,
                                                     float* __restrict__ out){
  __shared__ _Float16 hh[256];
  __shared__ float hfin[256];
  int tid = threadIdx.x;
  int i = tid >> 1;        // gate index 0..255
  int half = tid & 1;      // k-half

  h2_t wr[64], wz[64], wn[64];
  {
    const float2* w2 = (const float2*)whh;
    size_t base = (size_t)half * 64;
    const float2* pr = w2 + (size_t)i*128       + base;
    const float2* pz = w2 + (size_t)(i+256)*128 + base;
    const float2* pn = w2 + (size_t)(i+512)*128 + base;
    #pragma unroll
    for (int k = 0; k < 64; k++){
      float2 a = pr[k];
      float2 b = pz[k];
      float2 c = pn[k];
      wr[k] = h2_t{(_Float16)a.x, (_Float16)a.y};
      wz[k] = h2_t{(_Float16)b.x, (_Float16)b.y};
      wn[k] = h2_t{(_Float16)c.x, (_Float16)c.y};
    }
  }
  float bR = bhh[i], bZ = bhh[i+256], bN = bhh[i+512];
  float h = 0.f;

  for (int t = 0; t < 64; t++){
    if (half == 0) hh[i] = (_Float16)h;
    __syncthreads();
    float gxr = gx[t*768 + i];
    float gxz = gx[t*768 + 256 + i];
    float gxn = gx[t*768 + 512 + i];
    const h2_t* hp2 = ((const h2_t*)hh) + half*64;
    float accR = 0.f, accZ = 0.f, accN = 0.f;
    #pragma unroll
    for (int k = 0; k < 64; k++){
      h2_t hv = hp2[k];
#ifdef HAS_FDOT2
      accR = __builtin_amdgcn_fdot2(hv, wr[k], accR, false);
      accZ = __builtin_amdgcn_fdot2(hv, wz[k], accZ, false);
      accN = __builtin_amdgcn_fdot2(hv, wn[k], accN, false);
#else
      accR = fmaf((float)hv.x, (float)wr[k].x, accR);
      accR = fmaf((float)hv.y, (float)wr[k].y, accR);
      accZ = fmaf((float)hv.x, (float)wz[k].x, accZ);
      accZ = fmaf((float)hv.y, (float)wz[k].y, accZ);
      accN = fmaf((float)hv.x, (float)wn[k].x, accN);
      accN = fmaf((float)hv.y, (float)wn[k].y, accN);
#endif
    }
    accR += __shfl_xor(accR, 1);
    accZ += __shfl_xor(accZ, 1);
    accN += __shfl_xor(accN, 1);
    float r = 1.f/(1.f + expf(-(gxr + accR + bR)));
    float z = 1.f/(1.f + expf(-(gxz + accZ + bZ)));
    float n = tanhf(gxn + r*(accN + bN));
    float hnew = (1.f - z)*n + z*h;
    __syncthreads();
    h = hnew;
  }

  if (half == 0) hfin[i] = h;
  __syncthreads();
  if (tid < 16){
    float acc = bc[tid];
    const float* wrow = Wc + (size_t)tid*256;
    for (int k = 0; k < 256; k++) acc = fmaf(hfin[k], wrow[k], acc);
    out[tid] = acc;
  }
}

extern "C" void kernel_launch(void* const* d_in, const int* in_sizes, int n_in,
                              void* d_out, int out_size, void* d_ws, size_t ws_size,
                              hipStream_t stream){
  const float* x   = (const float*)d_in[0];
  const int*   ei  = (const int*)d_in[1];
  const int*   ptr = (const int*)d_in[2];
  const float* W1  = (const float*)d_in[3];
  const float* b1  = (const float*)d_in[4];
  const float* W2  = (const float*)d_in[5];
  const float* b2  = (const float*)d_in[6];
  const float* wih = (const float*)d_in[7];
  const float* whh = (const float*)d_in[8];
  const float* bih = (const float*)d_in[9];
  const float* bhh = (const float*)d_in[10];
  const float* Wc  = (const float*)d_in[11];
  const float* bc  = (const float*)d_in[12];
  float* outp = (float*)d_out;

  const int N = in_sizes[0] / 256;   // 100000
  const int E = in_sizes[1] / 2;     // 1600000

  char* w = (char*)d_ws;
  size_t off = 0;
  auto alloc = [&](size_t bytes){ void* p = w + off; off = align512(off + bytes); return p; };
  ushort_t* bufA = (ushort_t*)alloc((size_t)N*256*2);   // xw  (bf16)
  ushort_t* bufB = (ushort_t*)alloc((size_t)N*256*2);   // h   (bf16)
  float* dis  = (float*)alloc((size_t)N*4);
  int*   cnt  = (int*)  alloc((size_t)N*4);
  int*   rp   = (int*)  alloc((size_t)(N+1)*4);
  int*   bsum = (int*)  alloc(128*4);
  int*   csrc = (int*)  alloc((size_t)E*4);
  uint4* Wp1  = (uint4*)alloc(8192*16);
  uint4* Wp2  = (uint4*)alloc(8192*16);
  float* hp   = (float*)alloc((size_t)64*256*4);
  float* gxb  = (float*)alloc((size_t)64*768*4);
  (void)ws_size; (void)n_in; (void)out_size;

  hipMemsetAsync(cnt, 0, (size_t)N*4, stream);
  hipMemsetAsync(hp,  0, (size_t)64*256*4, stream);

  // CSR build + degree + weight packing
  count_kernel<<<(E+255)/256, 256, 0, stream>>>(ei, cnt, E);
  dis_kernel<<<(N+255)/256, 256, 0, stream>>>(cnt, dis, N);
  int nb = (N + 1023) / 1024;
  scan_block_kernel<<<nb, 1024, 0, stream>>>(cnt, rp, bsum, N);
  scan_sums_kernel<<<1, 128, 0, stream>>>(bsum, nb);
  add_off_kernel<<<(N+255)/256, 256, 0, stream>>>(rp, bsum, cnt, N);
  fill_kernel<<<(E+255)/256, 256, 0, stream>>>(ei, rp, cnt, csrc, E);
  packW_kernel<<<32, 256, 0, stream>>>(W1, Wp1);
  packW_kernel<<<32, 256, 0, stream>>>(W2, Wp2);

  // GCN layer 1
  gemm_mfma<false><<<dim3((N+127)/128, 2), 256, 0, stream>>>(x, Wp1, bufA, N);
  agg_kernel<<<(N+7)/8, 256, 0, stream>>>(bufA, dis, rp, csrc, b1, bufB, N);
  // GCN layer 2
  gemm_mfma<true><<<dim3((N+127)/128, 2), 256, 0, stream>>>(bufB, Wp2, bufA, N);
  agg_kernel<<<(N+7)/8, 256, 0, stream>>>(bufA, dis, rp, csrc, b2, bufB, N);

  // pool + GRU + classifier
  pool_kernel<<<dim3(64, 8), 256, 0, stream>>>(bufB, ptr, hp);
  hp_div_kernel<<<64, 256, 0, stream>>>(hp, ptr);
  gx_kernel<<<64, 768, 0, stream>>>(hp, wih, bih, gxb);
  gru_kernel<<<1, 512, 0, stream>>>(gxb, whh, bhh, Wc, bc, outp);
}

// Round 7
// 815.959 us; speedup vs baseline: 2.3893x; 1.1107x over previous
//
#include <hip/hip_runtime.h>
#include <hip/hip_bf16.h>
#include <math.h>

// Problem constants (fixed by reference): N=100000 nodes, E=1.6M edges, H=256, T=64.

static inline size_t align512(size_t x){ return (x + 511) & ~size_t(511); }

typedef _Float16 h2_t __attribute__((ext_vector_type(2)));
typedef unsigned short ushort_t;
typedef short bf16x8 __attribute__((ext_vector_type(8)));   // 8 bf16 = 4 VGPRs (MFMA A/B frag)
typedef float f32x4 __attribute__((ext_vector_type(4)));    // MFMA C/D frag
typedef float f32x2 __attribute__((ext_vector_type(2)));

#if defined(__has_builtin)
#if __has_builtin(__builtin_amdgcn_fdot2)
#define HAS_FDOT2 1
#endif
#if __has_builtin(__builtin_amdgcn_cvt_pk_f32_fp8) && __has_builtin(__builtin_amdgcn_cvt_pk_fp8_f32)
#define HAS_FP8CVT 1
#endif
#endif

__device__ inline ushort_t f2bf(float f){
  unsigned u = __float_as_uint(f);
  unsigned r = u + 0x7FFFu + ((u >> 16) & 1u);   // RTNE
  return (ushort_t)(r >> 16);
}
__device__ inline float bf2f(ushort_t h){ return __uint_as_float(((unsigned)h) << 16); }
__device__ inline unsigned pk2bf(float lo, float hi){
  return ((unsigned)f2bf(hi) << 16) | (unsigned)f2bf(lo);
}
__device__ inline bf16x8 as_bf16x8(uint4 u){
  union { uint4 u4; bf16x8 b; } c; c.u4 = u; return c.b;
}

// ---- fp8 e4m3 encode/decode (HW cvt on gfx950; SW fallback approximate) ----

__device__ inline unsigned char f2fp8(float x){
#ifdef HAS_FP8CVT
  int p = __builtin_amdgcn_cvt_pk_fp8_f32(x, x, 0, false);
  return (unsigned char)(p & 0xFF);
#else
  unsigned u = __float_as_uint(x);
  unsigned s = (u >> 24) & 0x80u;
  unsigned um = u & 0x7FFFFFFFu;
  if (um >= 0x43E00000u) return (unsigned char)(s | 0x7E);      // clamp to 448
  if (um <  0x3C000000u) return (unsigned char)s;               // flush < 2^-7
  unsigned r = um + 0x7FFFFu + ((um >> 20) & 1u);               // RTNE at bit 20
  unsigned e = (r >> 23) & 0xFF, m = (r >> 20) & 7u;
  return (unsigned char)(s | ((e - 120u) << 3) | m);
#endif
}
__device__ inline void fp8x4_to_f32(unsigned v, float& a, float& b, float& c, float& d){
#ifdef HAS_FP8CVT
  f32x2 lo = __builtin_amdgcn_cvt_pk_f32_fp8(v, false);
  f32x2 hi = __builtin_amdgcn_cvt_pk_f32_fp8(v, true);
  a = lo.x; b = lo.y; c = hi.x; d = hi.y;
#else
  auto d1 = [](unsigned char t)->float{
    unsigned s = (t >> 7) & 1u, e = (t >> 3) & 0xFu, m = t & 7u;
    float v = (e == 0) ? ldexpf((float)m, -9) : ldexpf(8.0f + (float)m, (int)e - 10);
    return s ? -v : v;
  };
  a = d1(v & 0xFF); b = d1((v >> 8) & 0xFF); c = d1((v >> 16) & 0xFF); d = d1(v >> 24);
#endif
}

// ---------- CSR build ----------

__global__ void count_kernel(const int* __restrict__ ei, int* __restrict__ cnt, int E){
  int e = blockIdx.x*256 + threadIdx.x;
  if (e < E) atomicAdd(&cnt[ei[E + e]], 1);
}

__global__ void dis_kernel(const int* __restrict__ cnt, float* __restrict__ dis, int N){
  int i = blockIdx.x*256 + threadIdx.x;
  if (i < N) dis[i] = rsqrtf((float)cnt[i] + 1.0f);
}

__global__ void scan_block_kernel(const int* __restrict__ cnt, int* __restrict__ rp,
                                  int* __restrict__ bsum, int N){
  __shared__ int s[2][1024];
  int t = threadIdx.x; int i = blockIdx.x*1024 + t;
  int v = (i < N) ? cnt[i] : 0;
  int cur = 0; s[0][t] = v; __syncthreads();
  for (int off = 1; off < 1024; off <<= 1){
    int nxt = cur ^ 1;
    int val = s[cur][t];
    if (t >= off) val += s[cur][t - off];
    s[nxt][t] = val; cur = nxt; __syncthreads();
  }
  if (i < N) rp[i+1] = s[cur][t];
  if (t == 1023) bsum[blockIdx.x] = s[cur][1023];
}

__global__ void scan_sums_kernel(int* __restrict__ bsum, int nb){
  __shared__ int s[128];
  int t = threadIdx.x;
  if (t < nb) s[t] = bsum[t];
  __syncthreads();
  if (t == 0){ int acc = 0; for (int b = 0; b < nb; b++){ int v = s[b]; s[b] = acc; acc += v; } }
  __syncthreads();
  if (t < nb) bsum[t] = s[t];
}

__global__ void add_off_kernel(int* __restrict__ rp, const int* __restrict__ bsum,
                               int* __restrict__ cnt, int N){
  int i = blockIdx.x*256 + threadIdx.x;
  if (i < N){ rp[i+1] += bsum[i >> 10]; cnt[i] = 0; }
  if (i == 0) rp[0] = 0;
}

__global__ void fill_kernel(const int* __restrict__ ei, const int* __restrict__ rp,
                            int* __restrict__ cnt, int* __restrict__ csrc, int E){
  int e = blockIdx.x*256 + threadIdx.x;
  if (e < E){
    int s = ei[e]; int d = ei[E + e];
    int pos = rp[d] + atomicAdd(&cnt[d], 1);
    csrc[pos] = s;
  }
}

// ---------- pack W (256x256 fp32 [k][n]) into MFMA B-fragment order (bf16) ----------

__global__ void packW_kernel(const float* __restrict__ W, uint4* __restrict__ Wp){
  int idx = blockIdx.x*256 + threadIdx.x;    // 0..8191
  int lane = idx & 63;
  int blk  = idx >> 6;                        // 0..127
  int q    = blk & 7;
  int t16  = blk >> 3;                        // 0..15 (16-col group)
  int n = t16*16 + (lane & 15);
  int k = q*32 + (lane >> 4)*8;
  uint4 v;
  v.x = pk2bf(W[(size_t)(k+0)*256 + n], W[(size_t)(k+1)*256 + n]);
  v.y = pk2bf(W[(size_t)(k+2)*256 + n], W[(size_t)(k+3)*256 + n]);
  v.z = pk2bf(W[(size_t)(k+4)*256 + n], W[(size_t)(k+5)*256 + n]);
  v.w = pk2bf(W[(size_t)(k+6)*256 + n], W[(size_t)(k+7)*256 + n]);
  Wp[idx] = v;
}

// ---------- MFMA GEMM: out[N,256](fp8 e4m3) = A[N,256] @ W[256,256] ----------
// 128x128 tile, 4 waves (2x2), each wave 64x64 via 4x4 tiles of 16x16x32 MFMA.
// B register-resident (128 VGPRs). A double-buffered in LDS. Out stored fp8
// (the consumer is the edge-gather, which is fabric-bytes-bound).

template<bool A_BF16>
__global__ __launch_bounds__(256, 2) void gemm_mfma(const void* __restrict__ Ap,
                                                    const uint4* __restrict__ Wp,
                                                    unsigned char* __restrict__ out, int N){
  __shared__ __align__(16) ushort_t As[2][128][40];
  int tid  = threadIdx.x;
  int lane = tid & 63;
  int wave = tid >> 6;
  int wr = wave >> 1, wc = wave & 1;
  int quad = lane >> 4;
  int l15  = lane & 15;
  int r0 = blockIdx.x * 128;
  int cb = blockIdx.y;

  uint4 bfr[4][8];
  {
    const uint4* wpb = Wp + (size_t)(cb*2 + wc) * 2048;
    #pragma unroll
    for (int ct = 0; ct < 4; ct++)
      #pragma unroll
      for (int q = 0; q < 8; q++)
        bfr[ct][q] = wpb[(ct*8 + q)*64 + lane];
  }

  f32x4 acc[4][4];
  #pragma unroll
  for (int rt = 0; rt < 4; rt++)
    #pragma unroll
    for (int ct = 0; ct < 4; ct++)
      acc[rt][ct] = f32x4{0.f, 0.f, 0.f, 0.f};

  int srow = tid >> 1;
  int shalf = tid & 1;
  int grow = min(r0 + srow, N - 1);

  auto load_stage = [&](int it, uint4& v0, uint4& v1){
    int k0 = it*32 + shalf*16;
    if constexpr (A_BF16){
      const ushort_t* Ab = (const ushort_t*)Ap;
      const uint4* ga = (const uint4*)(Ab + (size_t)grow*256 + k0);
      v0 = ga[0]; v1 = ga[1];
    } else {
      const float* Af = (const float*)Ap;
      const float4* ga = (const float4*)(Af + (size_t)grow*256 + k0);
      float4 f0 = ga[0], f1 = ga[1], f2 = ga[2], f3 = ga[3];
      v0.x = pk2bf(f0.x, f0.y); v0.y = pk2bf(f0.z, f0.w);
      v0.z = pk2bf(f1.x, f1.y); v0.w = pk2bf(f1.z, f1.w);
      v1.x = pk2bf(f2.x, f2.y); v1.y = pk2bf(f2.z, f2.w);
      v1.z = pk2bf(f3.x, f3.y); v1.w = pk2bf(f3.z, f3.w);
    }
  };
  auto write_stage = [&](int b, uint4 v0, uint4 v1){
    *(uint4*)&As[b][srow][shalf*16]     = v0;
    *(uint4*)&As[b][srow][shalf*16 + 8] = v1;
  };

  {
    uint4 v0, v1;
    load_stage(0, v0, v1);
    write_stage(0, v0, v1);
  }
  __syncthreads();

  #pragma unroll
  for (int it = 0; it < 8; it++){
    const int b = it & 1;
    uint4 n0, n1;
    if (it < 7) load_stage(it + 1, n0, n1);
    #pragma unroll
    for (int rt = 0; rt < 4; rt++){
      int arow = wr*64 + rt*16 + l15;
      uint4 av = *(const uint4*)&As[b][arow][quad*8];
      bf16x8 af = as_bf16x8(av);
      #pragma unroll
      for (int ct = 0; ct < 4; ct++)
        acc[rt][ct] = __builtin_amdgcn_mfma_f32_16x16x32_bf16(
            af, as_bf16x8(bfr[ct][it]), acc[rt][ct], 0, 0, 0);
    }
    if (it < 7){
      write_stage(b ^ 1, n0, n1);
      __syncthreads();
    }
  }

  // store C (fp8): row = r0+wr*64+rt*16+quad*4+g, col = cb*128+wc*64+ct*16+l15
  int crow0 = r0 + wr*64 + quad*4;
  int ccol0 = cb*128 + wc*64 + l15;
  #pragma unroll
  for (int rt = 0; rt < 4; rt++){
    #pragma unroll
    for (int g = 0; g < 4; g++){
      int row = crow0 + rt*16 + g;
      if (row < N){
        #pragma unroll
        for (int ct = 0; ct < 4; ct++)
          out[(size_t)row*256 + ccol0 + ct*16] = f2fp8(acc[rt][ct][g]);
      }
    }
  }
}

// ---------- GCN aggregation (fp8 gather -> bf16 out): half-wave (32 lanes) per
// node, 8 fp8 cols per lane as one 8B uint2 load (256B/row, fully coalesced).

__global__ __launch_bounds__(256) void agg_kernel(const unsigned char* __restrict__ xw,
                                                  const float* __restrict__ dis,
                                                  const int* __restrict__ rp,
                                                  const int* __restrict__ csrc,
                                                  const float* __restrict__ bias,
                                                  ushort_t* __restrict__ out, int N){
  int node = blockIdx.x*8 + (threadIdx.x >> 5);
  int lane = threadIdx.x & 31;
  if (node >= N) return;
  const uint2* xw2 = (const uint2*)xw;     // 8 B = 8 fp8; row = 32 uint2
  float di = dis[node];
  float sc = di * di;
  float acc[8];
  {
    uint2 a = xw2[(size_t)node*32 + lane];
    float v0,v1,v2,v3,v4,v5,v6,v7;
    fp8x4_to_f32(a.x, v0, v1, v2, v3);
    fp8x4_to_f32(a.y, v4, v5, v6, v7);
    acc[0]=v0*sc; acc[1]=v1*sc; acc[2]=v2*sc; acc[3]=v3*sc;
    acc[4]=v4*sc; acc[5]=v5*sc; acc[6]=v6*sc; acc[7]=v7*sc;
  }
  int e0 = rp[node], e1 = rp[node+1];
  for (int e = e0; e < e1; e++){
    int s = csrc[e];
    float cc = dis[s] * di;
    uint2 v = xw2[(size_t)s*32 + lane];
    float v0,v1,v2,v3,v4,v5,v6,v7;
    fp8x4_to_f32(v.x, v0, v1, v2, v3);
    fp8x4_to_f32(v.y, v4, v5, v6, v7);
    acc[0] = fmaf(v0, cc, acc[0]);
    acc[1] = fmaf(v1, cc, acc[1]);
    acc[2] = fmaf(v2, cc, acc[2]);
    acc[3] = fmaf(v3, cc, acc[3]);
    acc[4] = fmaf(v4, cc, acc[4]);
    acc[5] = fmaf(v5, cc, acc[5]);
    acc[6] = fmaf(v6, cc, acc[6]);
    acc[7] = fmaf(v7, cc, acc[7]);
  }
  const float4* b4 = (const float4*)bias;   // cols lane*8..lane*8+7
  float4 bA = b4[lane*2], bB = b4[lane*2+1];
  acc[0] = fmaxf(acc[0] + bA.x, 0.f);
  acc[1] = fmaxf(acc[1] + bA.y, 0.f);
  acc[2] = fmaxf(acc[2] + bA.z, 0.f);
  acc[3] = fmaxf(acc[3] + bA.w, 0.f);
  acc[4] = fmaxf(acc[4] + bB.x, 0.f);
  acc[5] = fmaxf(acc[5] + bB.y, 0.f);
  acc[6] = fmaxf(acc[6] + bB.z, 0.f);
  acc[7] = fmaxf(acc[7] + bB.w, 0.f);
  uint4 o;
  o.x = pk2bf(acc[0], acc[1]);
  o.y = pk2bf(acc[2], acc[3]);
  o.z = pk2bf(acc[4], acc[5]);
  o.w = pk2bf(acc[6], acc[7]);
  ((uint4*)out)[(size_t)node*32 + lane] = o;
}

// ---------- mean pool (bf16 input, fp32 accumulate) ----------

__global__ void pool_kernel(const ushort_t* __restrict__ h, const int* __restrict__ ptr,
                            float* __restrict__ hp){
  int t = blockIdx.x; int part = blockIdx.y; int c = threadIdx.x;
  int s0 = ptr[t], s1 = ptr[t+1];
  int len = s1 - s0;
  int chunk = (len + 7) / 8;
  int r0 = s0 + part*chunk;
  int r1 = min(r0 + chunk, s1);
  float acc = 0.f;
  for (int r = r0; r < r1; r++) acc += bf2f(h[(size_t)r*256 + c]);
  if (r1 > r0) atomicAdd(&hp[t*256 + c], acc);
}

__global__ void hp_div_kernel(float* __restrict__ hp, const int* __restrict__ ptr){
  int t = blockIdx.x; int c = threadIdx.x;
  float cf = (float)max(ptr[t+1] - ptr[t], 1);
  hp[t*256 + c] /= cf;
}

// ---------- GX[t,g] = dot(hp[t], w_ih[g]) + b_ih[g] ----------

__global__ __launch_bounds__(768) void gx_kernel(const float* __restrict__ hp,
                                                 const float* __restrict__ wih,
                                                 const float* __restrict__ bih,
                                                 float* __restrict__ gx){
  __shared__ float xs[256];
  int t = blockIdx.x; int g = threadIdx.x;
  if (g < 256) xs[g] = hp[t*256 + g];
  __syncthreads();
  float acc = bih[g];
  const float* wr = wih + (size_t)g*256;
  #pragma unroll 4
  for (int k = 0; k < 256; k++) acc = fmaf(xs[k], wr[k], acc);
  gx[t*768 + g] = acc;
}

// ---------- sequential GRU: single block, 512 threads, w_hh register-resident f16 ----------
// FULL unroll on the preload so wr/wz/wn promote to VGPRs (partial unroll -> scratch spill).

__global__ __launch_bounds__(512, 2) void gru_kernel(const float* __restrict__ gx,
                                                     const float* __restrict__ whh,
                                                     const float* __restrict__ bhh,
                                                     const float* __restrict__ Wc,
                                                     const float* __restrict__ bc,
                                                     float* __restrict__ out){
  __shared__ _Float16 hh[256];
  __shared__ float hfin[256];
  int tid = threadIdx.x;
  int i = tid >> 1;        // gate index 0..255
  int half = tid & 1;      // k-half

  h2_t wr[64], wz[64], wn[64];
  {
    const float2* w2 = (const float2*)whh;
    size_t base = (size_t)half * 64;
    const float2* pr = w2 + (size_t)i*128       + base;
    const float2* pz = w2 + (size_t)(i+256)*128 + base;
    const float2* pn = w2 + (size_t)(i+512)*128 + base;
    #pragma unroll
    for (int k = 0; k < 64; k++){
      float2 a = pr[k];
      float2 b = pz[k];
      float2 c = pn[k];
      wr[k] = h2_t{(_Float16)a.x, (_Float16)a.y};
      wz[k] = h2_t{(_Float16)b.x, (_Float16)b.y};
      wn[k] = h2_t{(_Float16)c.x, (_Float16)c.y};
    }
  }
  float bR = bhh[i], bZ = bhh[i+256], bN = bhh[i+512];
  float h = 0.f;

  for (int t = 0; t < 64; t++){
    if (half == 0) hh[i] = (_Float16)h;
    __syncthreads();
    float gxr = gx[t*768 + i];
    float gxz = gx[t*768 + 256 + i];
    float gxn = gx[t*768 + 512 + i];
    const h2_t* hp2 = ((const h2_t*)hh) + half*64;
    float accR = 0.f, accZ = 0.f, accN = 0.f;
    #pragma unroll
    for (int k = 0; k < 64; k++){
      h2_t hv = hp2[k];
#ifdef HAS_FDOT2
      accR = __builtin_amdgcn_fdot2(hv, wr[k], accR, false);
      accZ = __builtin_amdgcn_fdot2(hv, wz[k], accZ, false);
      accN = __builtin_amdgcn_fdot2(hv, wn[k], accN, false);
#else
      accR = fmaf((float)hv.x, (float)wr[k].x, accR);
      accR = fmaf((float)hv.y, (float)wr[k].y, accR);
      accZ = fmaf((float)hv.x, (float)wz[k].x, accZ);
      accZ = fmaf((float)hv.y, (float)wz[k].y, accZ);
      accN = fmaf((float)hv.x, (float)wn[k].x, accN);
      accN = fmaf((float)hv.y, (float)wn[k].y, accN);
#endif
    }
    accR += __shfl_xor(accR, 1);
    accZ += __shfl_xor(accZ, 1);
    accN += __shfl_xor(accN, 1);
    float r = 1.f/(1.f + expf(-(gxr + accR + bR)));
    float z = 1.f/(1.f + expf(-(gxz + accZ + bZ)));
    float n = tanhf(gxn + r*(accN + bN));
    float hnew = (1.f - z)*n + z*h;
    __syncthreads();
    h = hnew;
  }

  if (half == 0) hfin[i] = h;
  __syncthreads();
  if (tid < 16){
    float acc = bc[tid];
    const float* wrow = Wc + (size_t)tid*256;
    for (int k = 0; k < 256; k++) acc = fmaf(hfin[k], wrow[k], acc);
    out[tid] = acc;
  }
}

extern "C" void kernel_launch(void* const* d_in, const int* in_sizes, int n_in,
                              void* d_out, int out_size, void* d_ws, size_t ws_size,
                              hipStream_t stream){
  const float* x   = (const float*)d_in[0];
  const int*   ei  = (const int*)d_in[1];
  const int*   ptr = (const int*)d_in[2];
  const float* W1  = (const float*)d_in[3];
  const float* b1  = (const float*)d_in[4];
  const float* W2  = (const float*)d_in[5];
  const float* b2  = (const float*)d_in[6];
  const float* wih = (const float*)d_in[7];
  const float* whh = (const float*)d_in[8];
  const float* bih = (const float*)d_in[9];
  const float* bhh = (const float*)d_in[10];
  const float* Wc  = (const float*)d_in[11];
  const float* bc  = (const float*)d_in[12];
  float* outp = (float*)d_out;

  const int N = in_sizes[0] / 256;   // 100000
  const int E = in_sizes[1] / 2;     // 1600000

  char* w = (char*)d_ws;
  size_t off = 0;
  auto alloc = [&](size_t bytes){ void* p = w + off; off = align512(off + bytes); return p; };
  unsigned char* bufA = (unsigned char*)alloc((size_t)N*256);     // xw (fp8 e4m3)
  ushort_t*      bufB = (ushort_t*)alloc((size_t)N*256*2);        // h  (bf16)
  float* dis  = (float*)alloc((size_t)N*4);
  int*   cnt  = (int*)  alloc((size_t)N*4);
  int*   rp   = (int*)  alloc((size_t)(N+1)*4);
  int*   bsum = (int*)  alloc(128*4);
  int*   csrc = (int*)  alloc((size_t)E*4);
  uint4* Wp1  = (uint4*)alloc(8192*16);
  uint4* Wp2  = (uint4*)alloc(8192*16);
  float* hp   = (float*)alloc((size_t)64*256*4);
  float* gxb  = (float*)alloc((size_t)64*768*4);
  (void)ws_size; (void)n_in; (void)out_size;

  hipMemsetAsync(cnt, 0, (size_t)N*4, stream);
  hipMemsetAsync(hp,  0, (size_t)64*256*4, stream);

  // CSR build + degree + weight packing
  count_kernel<<<(E+255)/256, 256, 0, stream>>>(ei, cnt, E);
  dis_kernel<<<(N+255)/256, 256, 0, stream>>>(cnt, dis, N);
  int nb = (N + 1023) / 1024;
  scan_block_kernel<<<nb, 1024, 0, stream>>>(cnt, rp, bsum, N);
  scan_sums_kernel<<<1, 128, 0, stream>>>(bsum, nb);
  add_off_kernel<<<(N+255)/256, 256, 0, stream>>>(rp, bsum, cnt, N);
  fill_kernel<<<(E+255)/256, 256, 0, stream>>>(ei, rp, cnt, csrc, E);
  packW_kernel<<<32, 256, 0, stream>>>(W1, Wp1);
  packW_kernel<<<32, 256, 0, stream>>>(W2, Wp2);

  // GCN layer 1
  gemm_mfma<false><<<dim3((N+127)/128, 2), 256, 0, stream>>>(x, Wp1, bufA, N);
  agg_kernel<<<(N+7)/8, 256, 0, stream>>>(bufA, dis, rp, csrc, b1, bufB, N);
  // GCN layer 2
  gemm_mfma<true><<<dim3((N+127)/128, 2), 256, 0, stream>>>(bufB, Wp2, bufA, N);
  agg_kernel<<<(N+7)/8, 256, 0, stream>>>(bufA, dis, rp, csrc, b2, bufB, N);

  // pool + GRU + classifier
  pool_kernel<<<dim3(64, 8), 256, 0, stream>>>(bufB, ptr, hp);
  hp_div_kernel<<<64, 256, 0, stream>>>(hp, ptr);
  gx_kernel<<<64, 768, 0, stream>>>(hp, wih, bih, gxb);
  gru_kernel<<<1, 512, 0, stream>>>(gxb, whh, bhh, Wc, bc, outp);
}